// Round 20
// baseline (647.237 us; speedup 1.0000x reference)
//
#include <hip/hip_runtime.h>
#include <stdint.h>

typedef unsigned short u16;                                   // raw bf16 bits
typedef __bf16 v8bf __attribute__((ext_vector_type(8)));      // MFMA A/B frag
typedef float  v4f  __attribute__((ext_vector_type(4)));      // MFMA C/D frag
typedef u16    u16x4 __attribute__((ext_vector_type(4)));

#define MFMA(a,b,c) __builtin_amdgcn_mfma_f32_16x16x32_bf16((a),(b),(c),0,0,0)
#define LOG2E 1.4426950408889634f

static __device__ __forceinline__ float bf2f(u16 u) {
    union { unsigned i; float f; } v; v.i = ((unsigned)u) << 16; return v.f;
}
static __device__ __forceinline__ u16 f2bf(float f) {         // RNE (manual)
    union { float f; unsigned i; } v; v.f = f;
    unsigned u = v.i;
    return (u16)((u + 0x7FFFu + ((u >> 16) & 1u)) >> 16);
}
static __device__ __forceinline__ u16 bfc(float f) {          // RNE via HW cvt
    union { __bf16 h; u16 u; } c; c.h = (__bf16)f; return c.u;
}
// fp32 -> bf16 frag (8 elems)
static __device__ __forceinline__ v8bf load8f(const float* p) {
    union { u16 s[8]; v8bf v; } U;
    float4 a = *(const float4*)p;
    float4 b = *(const float4*)(p + 4);
    U.s[0] = bfc(a.x); U.s[1] = bfc(a.y); U.s[2] = bfc(a.z); U.s[3] = bfc(a.w);
    U.s[4] = bfc(b.x); U.s[5] = bfc(b.y); U.s[6] = bfc(b.z); U.s[7] = bfc(b.w);
    return U.v;
}
// dual-dtype helpers (slow path only)
static __device__ __forceinline__ v8bf load8(const void* base, size_t off, bool f32) {
    union { u16 s[8]; v8bf v; } U;
    if (f32) return load8f((const float*)base + off);
    U.v = *(const v8bf*)((const u16*)base + off);
    return U.v;
}
static __device__ __forceinline__ float load1(const void* base, size_t off, bool f32) {
    return f32 ? ((const float*)base)[off] : bf2f(((const u16*)base)[off]);
}

// ---- dtype probe (slow path only) ----
__global__ void probe_kernel(const unsigned* __restrict__ x, int* __restrict__ flag) {
    if (threadIdx.x == 0 && blockIdx.x == 0) {
        int b16like = 0;
        for (int i = 0; i < 128; i++) {
            unsigned lo = x[i] & 0xFFFFu;
            int e = (lo >> 7) & 0xFF;
            if (e >= 110 && e <= 140) b16like++;
        }
        *flag = (b16like >= 64) ? 0 : 1;   // 1 => fp32 inputs
    }
}

// =================== FAST PATH (fp32 inputs, uses workspace) ===================

// ---- K0: convert qkv + proj weights/biases to bf16. grid (256, 2) ----
__global__ __launch_bounds__(256) void wconv_kernel(
    const float* __restrict__ wqkvx, const float* __restrict__ bqkvx,
    const float* __restrict__ wqkvy, const float* __restrict__ bqkvy,
    const float* __restrict__ wpx, const float* __restrict__ bpx,
    const float* __restrict__ wpy, const float* __restrict__ bpy,
    u16* __restrict__ wb, u16* __restrict__ bb,
    u16* __restrict__ wpb, u16* __restrict__ bpb)
{
    const int s = blockIdx.y;
    const int i = blockIdx.x * 256 + threadIdx.x;      // [0, 65536)
    if (i < 49152) {
        wb[(size_t)s * 49152 + i] = bfc((s ? wqkvy : wqkvx)[i]);
    } else {
        wpb[(size_t)s * 16384 + (i - 49152)] = bfc((s ? wpy : wpx)[i - 49152]);
    }
    if (i < 384)       bb[s * 384 + i]          = bfc((s ? bqkvy : bqkvx)[i]);
    else if (i < 512)  bpb[s * 128 + (i - 384)] = bfc((s ? bpy : bpx)[i - 384]);
}

// ---- device bodies shared by mega + standalone kernels ----
static __device__ __forceinline__ void mask_body(
    int w, int s, const float* maskx, const float* masky, float* mskP, int tid)
{
    const float* m = s ? masky : maskx;
    const size_t base = (size_t)w * 15625;
    float* dst = mskP + ((size_t)s * 256 + w) * 16000;
    for (int i = tid; i < 16000; i += 256) {
        const int row = i >> 7;
        int col = i & 127; if (col > 124) col = 124;
        dst[i] = m[base + (size_t)row * 125 + col] * LOG2E;
    }
}
static __device__ __forceinline__ void rpb_body(
    int h, const float* rpb, float* rpbP, int tid)
{
    for (int i = tid; i < 16000; i += 256) {
        const int row = i >> 7;                   // query (< 125)
        int col = i & 127; if (col > 124) col = 124;
        const int p0 = row / 25, prem = row - p0 * 25, p1 = prem / 5, p2 = prem - p1 * 5;
        const int q0 = col / 25, qrem = col - q0 * 25, q1 = qrem / 5, q2 = qrem - q1 * 5;
        const int idx = (p0 - q0 + 4) * 81 + (p1 - q1 + 4) * 9 + (p2 - q2 + 4);
        rpbP[(size_t)h * 16000 + i] = rpb[(size_t)idx * 4 + h] * LOG2E;
    }
}
// combined (mask + rpb) * LOG2E table (r18 gather form; rpb is L1-resident 6KB)
static __device__ __forceinline__ void cmb_body(
    int w, int h, int s, const float* maskx, const float* masky,
    const float* rpb, float* cmb, int tid)
{
    const float* m = s ? masky : maskx;
    const size_t mbase = (size_t)w * 15625;
    float* dst = cmb + (((size_t)s * 256 + w) * 4 + h) * 16000;
    for (int i = tid; i < 16000; i += 256) {
        const int row = i >> 7;
        int col = i & 127; if (col > 124) col = 124;
        const int p0 = row / 25, prem = row - p0 * 25, p1 = prem / 5, p2 = prem - p1 * 5;
        const int q0 = col / 25, qrem = col - q0 * 25, q1 = qrem / 5, q2 = qrem - q1 * 5;
        const int idx = (p0 - q0 + 4) * 81 + (p1 - q1 + 4) * 9 + (p2 - q2 + 4);
        dst[i] = (m[mbase + (size_t)row * 125 + col] + rpb[(size_t)idx * 4 + h]) * LOG2E;
    }
}
// 256 tokens per block (64/wave, mt=0..3): weight fragments amortized 2x
static __device__ __forceinline__ void qkv_body(
    int mblk, int s, const float* x, const float* y,
    const u16* wb, const u16* bb,
    u16* q, u16* k, u16* vT, int tid)
{
    const float* A = s ? y : x;
    const u16* W  = wb + (size_t)s * 49152;
    const u16* Bb = bb + s * 384;
    const int lane = tid & 63, wv = tid >> 6;
    const int l15 = lane & 15, lg = lane >> 4;

    const int mbase = mblk * 256 + wv * 64;          // padded-m space [0, 262144)

    v8bf af[4][4];
    #pragma unroll
    for (int mt = 0; mt < 4; mt++) {
        const int mr = mbase + mt * 16 + l15;
        const int b  = mr >> 7;
        int n = mr & 127; if (n > 124) n = 124;      // clamp pad rows
        const float* arow = A + (size_t)(b * 125 + n) * 128;
        #pragma unroll
        for (int kk = 0; kk < 4; kk++)
            af[mt][kk] = load8f(arow + kk * 32 + lg * 8);
    }

    const v4f z4 = {0.f,0.f,0.f,0.f};
    #pragma unroll
    for (int nt = 0; nt < 24; nt++) {
        const int col0 = nt * 16;
        v8bf bfr[4];
        #pragma unroll
        for (int kk = 0; kk < 4; kk++)
            bfr[kk] = *(const v8bf*)(W + (size_t)(col0 + l15) * 128 + kk * 32 + lg * 8);

        const int three = col0 >> 7;                 // 0=q 1=k 2=v
        const int h     = (col0 >> 5) & 3;

        if (three < 2) {
            // q/k: SWAPPED MFMA -> D[channel][token]; packed u16x4 stores
            float bv[4];
            {
                const u16x4 bq = *(const u16x4*)&Bb[col0 + 4 * lg];
                #pragma unroll
                for (int r = 0; r < 4; r++) bv[r] = bf2f(bq[r]);
            }
            u16* dst = (three == 0) ? q : k;
            const int d0 = (col0 & 31) + 4 * lg;
            #pragma unroll
            for (int mt = 0; mt < 4; mt++) {
                v4f a0 = z4;
                #pragma unroll
                for (int kk = 0; kk < 4; kk++)
                    a0 = MFMA(bfr[kk], af[mt][kk], a0);
                const int t = mbase + mt * 16 + l15;
                const int b = t >> 7;
                int n = t & 127; if (n > 124) n = 124;   // dup-write same value
                const size_t hb = (size_t)(s * 2048 + b) * 4 + h;
                u16x4 pk;
                #pragma unroll
                for (int ri = 0; ri < 4; ri++) pk[ri] = bfc(a0[ri] + bv[ri]);
                *(u16x4*)&dst[hb * 4000 + n * 32 + d0] = pk;
            }
        } else {
            // v: unswapped -> vT packed store
            const float bv = bf2f(Bb[col0 + l15]);
            const int d = (col0 & 31) + l15;
            #pragma unroll
            for (int mt = 0; mt < 4; mt++) {
                v4f a0 = z4;
                #pragma unroll
                for (int kk = 0; kk < 4; kk++)
                    a0 = MFMA(af[mt][kk], bfr[kk], a0);
                const int m0 = mbase + mt * 16 + lg * 4;
                const int b  = m0 >> 7;
                const int n0 = m0 & 127;
                const size_t hb = (size_t)(s * 2048 + b) * 4 + h;
                u16x4 pk;
                #pragma unroll
                for (int ri = 0; ri < 4; ri++) pk[ri] = bfc(a0[ri] + bv);
                *(u16x4*)&vT[hb * 4096 + (size_t)d * 128 + n0] = pk;
            }
        }
    }
}

// ---- K2c (tier D): fused qkv + combined-table builder. grid (2048, 2).
// INTERLEAVED roles: even bx -> cmb slice, odd bx -> qkv tile, so every CU
// holds a mix of memory-only and MFMA-heavy blocks (pipe overlap). ----
__global__ __launch_bounds__(256) void qkvc_kernel(
    const float* __restrict__ x, const float* __restrict__ y,
    const u16* __restrict__ wb, const u16* __restrict__ bb,
    const float* __restrict__ maskx, const float* __restrict__ masky,
    const float* __restrict__ rpb,
    u16* __restrict__ q, u16* __restrict__ k, u16* __restrict__ vT,
    float* __restrict__ cmb)
{
    const int bx = blockIdx.x, by = blockIdx.y, tid = threadIdx.x;
    const int idx = bx >> 1;                      // [0, 1024)
    if ((bx & 1) == 0) cmb_body(idx >> 2, idx & 3, by, maskx, masky, rpb, cmb, tid);
    else               qkv_body(idx, by, x, y, wb, bb, q, k, vT, tid);
}

// ---- K2a (tier A): fused qkv + split table builders. grid (1282, 2) ----
__global__ __launch_bounds__(256) void qkvt_kernel(
    const float* __restrict__ x, const float* __restrict__ y,
    const u16* __restrict__ wb, const u16* __restrict__ bb,
    const float* __restrict__ maskx, const float* __restrict__ masky,
    const float* __restrict__ rpb,
    u16* __restrict__ q, u16* __restrict__ k, u16* __restrict__ vT,
    float* __restrict__ mskP, float* __restrict__ rpbP)
{
    const int bx = blockIdx.x, by = blockIdx.y, tid = threadIdx.x;
    if (bx < 256)       mask_body(bx, by, maskx, masky, mskP, tid);
    else if (bx < 258)  rpb_body((bx - 256) * 2 + by, rpb, rpbP, tid);
    else                qkv_body(bx - 258, by, x, y, wb, bb, q, k, vT, tid);
}

// ---- K2b (tier B/C): standalone qkv. grid (1024, 2) ----
__global__ __launch_bounds__(256) void qkv_kernel(
    const float* __restrict__ x, const float* __restrict__ y,
    const u16* __restrict__ wb, const u16* __restrict__ bb,
    u16* __restrict__ q, u16* __restrict__ k, u16* __restrict__ vT)
{
    qkv_body(blockIdx.x, blockIdx.y, x, y, wb, bb, q, k, vT, threadIdx.x);
}

// ---- standalone table kernels ----
__global__ __launch_bounds__(256) void mskp_kernel(
    const float* __restrict__ maskx, const float* __restrict__ masky,
    float* __restrict__ mskP)
{
    mask_body(blockIdx.x, blockIdx.y, maskx, masky, mskP, threadIdx.x);
}
__global__ __launch_bounds__(256) void rpbp_kernel(
    const float* __restrict__ rpb, float* __restrict__ rpbP)
{
    rpb_body(blockIdx.x, rpb, rpbP, threadIdx.x);
}

// ---- K1 (mid tier): rpbT[h][col(key)][row(query) pad128] fp32 (col-major) ----
__global__ __launch_bounds__(256) void rpbt_kernel(
    const float* __restrict__ rpb, float* __restrict__ rpbT)
{
    const int h = blockIdx.x;
    for (int i = threadIdx.x; i < 16000; i += 256) {
        const int col = i >> 7, row = i & 127;
        float v = 0.f;
        if (row < 125) {
            const int p0 = row / 25, prem = row - p0 * 25, p1 = prem / 5, p2 = prem - p1 * 5;
            const int q0 = col / 25, qrem = col - q0 * 25, q1 = qrem / 5, q2 = qrem - q1 * 5;
            const int idx = (p0 - q0 + 4) * 81 + (p1 - q1 + 4) * 9 + (p2 - q2 + 4);
            v = rpb[(size_t)idx * 4 + h];
        }
        rpbT[(size_t)h * 16000 + i] = v;
    }
}

// ---- K3 (tier D): attn with COMBINED table (frozen r18 form, ~240 us) ----
__global__ __launch_bounds__(256) void attn_cmb(
    const u16* __restrict__ q, const u16* __restrict__ k, const u16* __restrict__ vT,
    const float* __restrict__ cmb,
    const u16* __restrict__ wpb, const u16* __restrict__ bpb,
    float* __restrict__ out)
{
    const int bid = blockIdx.x;                    // 4096 = 8 xcd * 512
    const int rep = (bid >> 3) & 15;               // same-w blocks -> same XCD
    const int w   = ((bid >> 7) << 3) | (bid & 7);
    const int s = rep & 1, b = (rep >> 1) * 256 + w;
    const int tid = threadIdx.x;
    const int hv = tid >> 6;                       // wave = head
    const int lane = tid & 63, l15 = lane & 15, lg = lane >> 4;

    __shared__ u16 Pl[4][16][140];                 // per-wave P^T slab (17920 B)
    __shared__ u16 Olds[32][136];                  // shared O tile (8704 B)
    u16* P = &Pl[hv][0][0];

    const u16* qb = q  + ((size_t)(s * 2048 + b) * 4 + hv) * 4000;
    const u16* kb = k  + ((size_t)((1 - s) * 2048 + b) * 4 + hv) * 4000;
    const u16* vb = vT + ((size_t)((1 - s) * 2048 + b) * 4 + hv) * 4096;
    const float* tP = cmb + (((size_t)s * 256 + w) * 4 + hv) * 16000;
    const u16* Wp = wpb + (size_t)s * 16384;       // [c][d] bf16
    float bpv[2];
    #pragma unroll
    for (int n2 = 0; n2 < 2; n2++)
        bpv[n2] = bf2f(bpb[s * 128 + hv * 32 + n2 * 16 + l15]);

    v8bf kf[8];                                    // resident K frags (A-operand)
    #pragma unroll
    for (int jt = 0; jt < 8; jt++) {
        int c = jt * 16 + l15; if (c > 124) c = 124;
        kf[jt] = *(const v8bf*)(kb + c * 32 + lg * 8);
    }

    const float scale2 = 0.17677669529663689f * LOG2E;   // 32^-0.5 * log2(e)
    const v4f z4 = {0.f,0.f,0.f,0.f};

    for (int ch = 0; ch < 4; ch++) {
        v4f ot[2][2];                              // O^T accum [mt][n2]
        float rinv[2];

        #pragma unroll
        for (int mt = 0; mt < 2; mt++) {
            int qr = ch * 32 + mt * 16 + l15; if (qr > 124) qr = 124;
            const v8bf qf = *(const v8bf*)(qb + qr * 32 + lg * 8);

            v4f acc[8];
            #pragma unroll
            for (int jt = 0; jt < 8; jt++) acc[jt] = z4;
            #pragma unroll
            for (int jt = 0; jt < 8; jt++)
                acc[jt] = MFMA(kf[jt], qf, acc[jt]);   // SWAPPED: D[key][qrow]

            // combined bias+mask (log2-domain), ONE float4 per jt
            const float* trow = tP + (size_t)qr * 128 + 4 * lg;
            #pragma unroll
            for (int jt = 0; jt < 8; jt++) {
                const float4 tb4 = *(const float4*)(trow + jt * 16);
                #pragma unroll
                for (int ri = 0; ri < 4; ri++) {
                    float t = fmaf(acc[jt][ri], scale2, (&tb4.x)[ri]);
                    if (jt == 7) t = (4 * lg + ri < 13) ? t : -1e30f;  // key >= 125
                    acc[jt][ri] = t;
                }
            }

            // lane-local softmax (row = l15), 2-shfl reduce across lg groups
            float mx = acc[0][0];
            #pragma unroll
            for (int jt = 0; jt < 8; jt++)
                #pragma unroll
                for (int ri = 0; ri < 4; ri++) mx = fmaxf(mx, acc[jt][ri]);
            mx = fmaxf(mx, __shfl_xor(mx, 16));
            mx = fmaxf(mx, __shfl_xor(mx, 32));
            float sum = 0.f;
            #pragma unroll
            for (int jt = 0; jt < 8; jt++)
                #pragma unroll
                for (int ri = 0; ri < 4; ri++) {
                    const float pv = __builtin_amdgcn_exp2f(acc[jt][ri] - mx);
                    acc[jt][ri] = pv; sum += pv;
                }
            sum += __shfl_xor(sum, 16);
            sum += __shfl_xor(sum, 32);
            rinv[mt] = 1.0f / sum;                 // lane-scalar (qrow = l15)

            // pack P^T (bf16 pairs) into wave-local LDS: P[l15][key]
            #pragma unroll
            for (int jt = 0; jt < 8; jt++) {
                const int kb2 = jt * 16 + 4 * lg;
                const unsigned w0 = (unsigned)f2bf(acc[jt][0]) | ((unsigned)f2bf(acc[jt][1]) << 16);
                const unsigned w1 = (unsigned)f2bf(acc[jt][2]) | ((unsigned)f2bf(acc[jt][3]) << 16);
                *(unsigned*)&P[l15 * 140 + kb2]     = w0;
                *(unsigned*)&P[l15 * 140 + kb2 + 2] = w1;
            }

            // PV swapped: A = V^T frag (vT natural layout), B = P^T frag
            ot[mt][0] = z4; ot[mt][1] = z4;
            #pragma unroll
            for (int kk = 0; kk < 4; kk++) {
                const v8bf pb = *(const v8bf*)&P[l15 * 140 + kk * 32 + lg * 8];
                #pragma unroll
                for (int n2 = 0; n2 < 2; n2++) {
                    const v8bf va = *(const v8bf*)(vb + (n2 * 16 + l15) * 128 + kk * 32 + lg * 8);
                    ot[mt][n2] = MFMA(va, pb, ot[mt][n2]);
                }
            }
        }

        __syncthreads();                           // prior proj reads of Olds done
        // O^T -> Olds[chunk row][channel], rinv folded (lane-scalar), packed b32
        #pragma unroll
        for (int mt = 0; mt < 2; mt++)
            #pragma unroll
            for (int n2 = 0; n2 < 2; n2++) {
                const int row = mt * 16 + l15;
                const int col = hv * 32 + n2 * 16 + 4 * lg;
                const unsigned w0 = (unsigned)f2bf(ot[mt][n2][0] * rinv[mt])
                                  | ((unsigned)f2bf(ot[mt][n2][1] * rinv[mt]) << 16);
                const unsigned w1 = (unsigned)f2bf(ot[mt][n2][2] * rinv[mt])
                                  | ((unsigned)f2bf(ot[mt][n2][3] * rinv[mt]) << 16);
                *(unsigned*)&Olds[row][col]     = w0;
                *(unsigned*)&Olds[row][col + 2] = w1;
            }
        __syncthreads();                           // O tile complete

        // ---- fused projection: this wave's 32 output cols ----
        v8bf wf[2][4];
        #pragma unroll
        for (int n2 = 0; n2 < 2; n2++)
            #pragma unroll
            for (int kk = 0; kk < 4; kk++)
                wf[n2][kk] = *(const v8bf*)(Wp + (size_t)(hv * 32 + n2 * 16 + l15) * 128
                                            + kk * 32 + lg * 8);
        v4f po[2][2];
        #pragma unroll
        for (int mt = 0; mt < 2; mt++)
            #pragma unroll
            for (int n2 = 0; n2 < 2; n2++) po[mt][n2] = z4;
        #pragma unroll
        for (int mt = 0; mt < 2; mt++) {
            v8bf af[4];
            #pragma unroll
            for (int kk = 0; kk < 4; kk++)
                af[kk] = *(const v8bf*)&Olds[mt * 16 + l15][kk * 32 + lg * 8];
            #pragma unroll
            for (int n2 = 0; n2 < 2; n2++)
                #pragma unroll
                for (int kk = 0; kk < 4; kk++)
                    po[mt][n2] = MFMA(af[kk], wf[n2][kk], po[mt][n2]);
        }

        #pragma unroll
        for (int mt = 0; mt < 2; mt++)
            #pragma unroll
            for (int n2 = 0; n2 < 2; n2++)
                #pragma unroll
                for (int ri = 0; ri < 4; ri++) {
                    const int row = ch * 32 + mt * 16 + lg * 4 + ri;
                    if (row < 125)
                        out[((size_t)s * 256000 + (size_t)b * 125 + row) * 128
                            + hv * 32 + n2 * 16 + l15] = po[mt][n2][ri] + bpv[n2];
                }
        __syncthreads();                           // proj reads done before next chunk
    }
}

// ---- K3 (tiers A/B): EXACT r13/r15 frozen attn ----
__global__ __launch_bounds__(256) void attn_swp(
    const u16* __restrict__ q, const u16* __restrict__ k, const u16* __restrict__ vT,
    const float* __restrict__ mskP, const float* __restrict__ rpbP,
    const u16* __restrict__ wpb, const u16* __restrict__ bpb,
    float* __restrict__ out)
{
    const int bid = blockIdx.x;
    const int rep = (bid >> 3) & 15;
    const int w   = ((bid >> 7) << 3) | (bid & 7);
    const int s = rep & 1, b = (rep >> 1) * 256 + w;
    const int tid = threadIdx.x;
    const int hv = tid >> 6;
    const int lane = tid & 63, l15 = lane & 15, lg = lane >> 4;

    __shared__ u16 Pl[4][16][140];
    __shared__ u16 Olds[32][136];
    u16* P = &Pl[hv][0][0];

    const u16* qb = q  + ((size_t)(s * 2048 + b) * 4 + hv) * 4000;
    const u16* kb = k  + ((size_t)((1 - s) * 2048 + b) * 4 + hv) * 4000;
    const u16* vb = vT + ((size_t)((1 - s) * 2048 + b) * 4 + hv) * 4096;
    const float* mP = mskP + ((size_t)s * 256 + w) * 16000;
    const float* rP = rpbP + (size_t)hv * 16000;
    const u16* Wp = wpb + (size_t)s * 16384;
    float bpv[2];
    #pragma unroll
    for (int n2 = 0; n2 < 2; n2++)
        bpv[n2] = bf2f(bpb[s * 128 + hv * 32 + n2 * 16 + l15]);

    v8bf kf[8];
    #pragma unroll
    for (int jt = 0; jt < 8; jt++) {
        int c = jt * 16 + l15; if (c > 124) c = 124;
        kf[jt] = *(const v8bf*)(kb + c * 32 + lg * 8);
    }

    const float scale2 = 0.17677669529663689f * LOG2E;
    const v4f z4 = {0.f,0.f,0.f,0.f};

    for (int ch = 0; ch < 4; ch++) {
        v4f ot[2][2];
        float rinv[2];

        #pragma unroll
        for (int mt = 0; mt < 2; mt++) {
            int qr = ch * 32 + mt * 16 + l15; if (qr > 124) qr = 124;
            const v8bf qf = *(const v8bf*)(qb + qr * 32 + lg * 8);

            v4f acc[8];
            #pragma unroll
            for (int jt = 0; jt < 8; jt++) acc[jt] = z4;
            #pragma unroll
            for (int jt = 0; jt < 8; jt++)
                acc[jt] = MFMA(kf[jt], qf, acc[jt]);

            const float* rrow = rP + (size_t)qr * 128 + 4 * lg;
            const float* mrow = mP + (size_t)qr * 128 + 4 * lg;
            #pragma unroll
            for (int jt = 0; jt < 8; jt++) {
                const float4 rb4 = *(const float4*)(rrow + jt * 16);
                const float4 mv4 = *(const float4*)(mrow + jt * 16);
                #pragma unroll
                for (int ri = 0; ri < 4; ri++) {
                    float t = fmaf(acc[jt][ri], scale2, (&rb4.x)[ri] + (&mv4.x)[ri]);
                    if (jt == 7) t = (4 * lg + ri < 13) ? t : -1e30f;
                    acc[jt][ri] = t;
                }
            }

            float mx = acc[0][0];
            #pragma unroll
            for (int jt = 0; jt < 8; jt++)
                #pragma unroll
                for (int ri = 0; ri < 4; ri++) mx = fmaxf(mx, acc[jt][ri]);
            mx = fmaxf(mx, __shfl_xor(mx, 16));
            mx = fmaxf(mx, __shfl_xor(mx, 32));
            float sum = 0.f;
            #pragma unroll
            for (int jt = 0; jt < 8; jt++)
                #pragma unroll
                for (int ri = 0; ri < 4; ri++) {
                    const float pv = __builtin_amdgcn_exp2f(acc[jt][ri] - mx);
                    acc[jt][ri] = pv; sum += pv;
                }
            sum += __shfl_xor(sum, 16);
            sum += __shfl_xor(sum, 32);
            rinv[mt] = 1.0f / sum;

            #pragma unroll
            for (int jt = 0; jt < 8; jt++) {
                const int kb2 = jt * 16 + 4 * lg;
                const unsigned w0 = (unsigned)f2bf(acc[jt][0]) | ((unsigned)f2bf(acc[jt][1]) << 16);
                const unsigned w1 = (unsigned)f2bf(acc[jt][2]) | ((unsigned)f2bf(acc[jt][3]) << 16);
                *(unsigned*)&P[l15 * 140 + kb2]     = w0;
                *(unsigned*)&P[l15 * 140 + kb2 + 2] = w1;
            }

            ot[mt][0] = z4; ot[mt][1] = z4;
            #pragma unroll
            for (int kk = 0; kk < 4; kk++) {
                const v8bf pb = *(const v8bf*)&P[l15 * 140 + kk * 32 + lg * 8];
                #pragma unroll
                for (int n2 = 0; n2 < 2; n2++) {
                    const v8bf va = *(const v8bf*)(vb + (n2 * 16 + l15) * 128 + kk * 32 + lg * 8);
                    ot[mt][n2] = MFMA(va, pb, ot[mt][n2]);
                }
            }
        }

        __syncthreads();
        #pragma unroll
        for (int mt = 0; mt < 2; mt++)
            #pragma unroll
            for (int n2 = 0; n2 < 2; n2++) {
                const int row = mt * 16 + l15;
                const int col = hv * 32 + n2 * 16 + 4 * lg;
                const unsigned w0 = (unsigned)f2bf(ot[mt][n2][0] * rinv[mt])
                                  | ((unsigned)f2bf(ot[mt][n2][1] * rinv[mt]) << 16);
                const unsigned w1 = (unsigned)f2bf(ot[mt][n2][2] * rinv[mt])
                                  | ((unsigned)f2bf(ot[mt][n2][3] * rinv[mt]) << 16);
                *(unsigned*)&Olds[row][col]     = w0;
                *(unsigned*)&Olds[row][col + 2] = w1;
            }
        __syncthreads();

        v8bf wf[2][4];
        #pragma unroll
        for (int n2 = 0; n2 < 2; n2++)
            #pragma unroll
            for (int kk = 0; kk < 4; kk++)
                wf[n2][kk] = *(const v8bf*)(Wp + (size_t)(hv * 32 + n2 * 16 + l15) * 128
                                            + kk * 32 + lg * 8);
        v4f po[2][2];
        #pragma unroll
        for (int mt = 0; mt < 2; mt++)
            #pragma unroll
            for (int n2 = 0; n2 < 2; n2++) po[mt][n2] = z4;
        #pragma unroll
        for (int mt = 0; mt < 2; mt++) {
            v8bf af[4];
            #pragma unroll
            for (int kk = 0; kk < 4; kk++)
                af[kk] = *(const v8bf*)&Olds[mt * 16 + l15][kk * 32 + lg * 8];
            #pragma unroll
            for (int n2 = 0; n2 < 2; n2++)
                #pragma unroll
                for (int kk = 0; kk < 4; kk++)
                    po[mt][n2] = MFMA(af[kk], wf[n2][kk], po[mt][n2]);
        }

        #pragma unroll
        for (int mt = 0; mt < 2; mt++)
            #pragma unroll
            for (int n2 = 0; n2 < 2; n2++)
                #pragma unroll
                for (int ri = 0; ri < 4; ri++) {
                    const int row = ch * 32 + mt * 16 + lg * 4 + ri;
                    if (row < 125)
                        out[((size_t)s * 256000 + (size_t)b * 125 + row) * 128
                            + hv * 32 + n2 * 16 + l15] = po[mt][n2][ri] + bpv[n2];
                }
        __syncthreads();
    }
}

// ---- K3 (mid tier): round-8 validated kernel (mask staged in LDS), fp32 in ----
__global__ __launch_bounds__(256) void attn_mld_kernel(
    const u16* __restrict__ q, const u16* __restrict__ k, const u16* __restrict__ vT,
    const float* __restrict__ maskx, const float* __restrict__ masky,
    const float* __restrict__ rpbT,
    const u16* __restrict__ wpb, const u16* __restrict__ bpb,
    float* __restrict__ out)
{
    const int bid = blockIdx.x;
    const int rep = (bid >> 3) & 15;
    const int w   = ((bid >> 7) << 3) | (bid & 7);
    const int s = rep & 1, b = (rep >> 1) * 256 + w;
    const int tid = threadIdx.x;
    const int hv = tid >> 6;
    const int lane = tid & 63, l15 = lane & 15, lg = lane >> 4;

    __shared__ u16 Pb[4][32][136];
    __shared__ float Mld[32][132];
    u16* P    = &Pb[hv][0][0];
    u16* Olds = &Pb[0][0][0];

    const u16* qb = q  + ((size_t)(s * 2048 + b) * 4 + hv) * 4000;
    const u16* kb = k  + ((size_t)((1 - s) * 2048 + b) * 4 + hv) * 4000;
    const u16* vb = vT + ((size_t)((1 - s) * 2048 + b) * 4 + hv) * 4096;
    const float* msk = s ? masky : maskx;
    const size_t mbase = (size_t)w * 15625;
    const float* rT = rpbT + (size_t)hv * 16000;
    const u16* Wp = wpb + (size_t)s * 16384;
    float bpv[2];
    #pragma unroll
    for (int n2 = 0; n2 < 2; n2++)
        bpv[n2] = bf2f(bpb[s * 128 + hv * 32 + n2 * 16 + l15]);

    int colc[8];
    #pragma unroll
    for (int jt = 0; jt < 8; jt++) {
        int c = jt * 16 + l15; if (c > 124) c = 124;
        colc[jt] = c;
    }

    v8bf kf[8];
    #pragma unroll
    for (int jt = 0; jt < 8; jt++)
        kf[jt] = *(const v8bf*)(kb + colc[jt] * 32 + lg * 8);

    const float scale = 0.17677669529663689f;
    const v4f z4 = {0.f,0.f,0.f,0.f};

    for (int ch = 0; ch < 4; ch++) {
        for (int i = tid; i < 4096; i += 256) {
            const int r = i >> 7, c = i & 127;
            int rc = ch * 32 + r; if (rc > 124) rc = 124;
            int cc = c;          if (cc > 124) cc = 124;
            Mld[r][c] = msk[mbase + (size_t)rc * 125 + cc];
        }
        __syncthreads();

        float rinv[2][4];
        #pragma unroll
        for (int mt = 0; mt < 2; mt++) {
            int qr = ch * 32 + mt * 16 + l15; if (qr > 124) qr = 124;
            const v8bf qf = *(const v8bf*)(qb + qr * 32 + lg * 8);

            v4f acc[8];
            #pragma unroll
            for (int jt = 0; jt < 8; jt++) acc[jt] = z4;
            #pragma unroll
            for (int jt = 0; jt < 8; jt++)
                acc[jt] = MFMA(qf, kf[jt], acc[jt]);

            const int rloc = mt * 16 + lg * 4;
            const int rowb = ch * 32 + rloc;
            const bool tail = (ch == 3) && (mt == 1);

            #pragma unroll
            for (int jt = 0; jt < 8; jt++) {
                const float4 c4 = *(const float4*)(rT + colc[jt] * 128 + rowb);
                #pragma unroll
                for (int ri = 0; ri < 4; ri++) {
                    const float mv = Mld[rloc + ri][jt * 16 + l15];
                    const float t = fmaf(acc[jt][ri], scale, (&c4.x)[ri] + mv);
                    const bool rv = !tail || (rowb + ri < 125);
                    const bool cv = (jt < 7) | (l15 < 13);
                    acc[jt][ri] = (rv & cv) ? t : -1e30f;
                }
            }

            #pragma unroll
            for (int ri = 0; ri < 4; ri++) {
                float mx = acc[0][ri];
                #pragma unroll
                for (int jt = 1; jt < 8; jt++) mx = fmaxf(mx, acc[jt][ri]);
                mx = fmaxf(mx, __shfl_xor(mx, 1));
                mx = fmaxf(mx, __shfl_xor(mx, 2));
                mx = fmaxf(mx, __shfl_xor(mx, 4));
                mx = fmaxf(mx, __shfl_xor(mx, 8));
                float sum = 0.f;
                #pragma unroll
                for (int jt = 0; jt < 8; jt++) {
                    const float pv = __expf(acc[jt][ri] - mx);
                    acc[jt][ri] = pv; sum += pv;
                }
                sum += __shfl_xor(sum, 1);
                sum += __shfl_xor(sum, 2);
                sum += __shfl_xor(sum, 4);
                sum += __shfl_xor(sum, 8);
                rinv[mt][ri] = 1.0f / sum;
            }

            #pragma unroll
            for (int jt = 0; jt < 8; jt++)
                #pragma unroll
                for (int ri = 0; ri < 4; ri++)
                    P[(rloc + ri) * 136 + jt * 16 + l15] = f2bf(acc[jt][ri]);
        }

        v8bf vf[2][4];
        #pragma unroll
        for (int n2 = 0; n2 < 2; n2++)
            #pragma unroll
            for (int kk = 0; kk < 4; kk++)
                vf[n2][kk] = *(const v8bf*)(vb + (n2 * 16 + l15) * 128 + kk * 32 + lg * 8);

        v4f o[2][2];
        #pragma unroll
        for (int mt = 0; mt < 2; mt++)
            #pragma unroll
            for (int n2 = 0; n2 < 2; n2++) o[mt][n2] = z4;
        #pragma unroll
        for (int mt = 0; mt < 2; mt++) {
            v8bf pa[4];
            #pragma unroll
            for (int kk = 0; kk < 4; kk++)
                pa[kk] = *(const v8bf*)&P[(mt * 16 + l15) * 136 + kk * 32 + lg * 8];
            #pragma unroll
            for (int n2 = 0; n2 < 2; n2++)
                #pragma unroll
                for (int kk = 0; kk < 4; kk++)
                    o[mt][n2] = MFMA(pa[kk], vf[n2][kk], o[mt][n2]);
        }

        __syncthreads();
        #pragma unroll
        for (int mt = 0; mt < 2; mt++)
            #pragma unroll
            for (int n2 = 0; n2 < 2; n2++)
                #pragma unroll
                for (int ri = 0; ri < 4; ri++)
                    Olds[(mt * 16 + lg * 4 + ri) * 136 + hv * 32 + n2 * 16 + l15] =
                        f2bf(o[mt][n2][ri] * rinv[mt][ri]);
        __syncthreads();

        v8bf wf[2][4];
        #pragma unroll
        for (int n2 = 0; n2 < 2; n2++)
            #pragma unroll
            for (int kk = 0; kk < 4; kk++)
                wf[n2][kk] = *(const v8bf*)(Wp + (size_t)(hv * 32 + n2 * 16 + l15) * 128
                                            + kk * 32 + lg * 8);
        v4f po[2][2];
        #pragma unroll
        for (int mt = 0; mt < 2; mt++)
            #pragma unroll
            for (int n2 = 0; n2 < 2; n2++) po[mt][n2] = z4;
        #pragma unroll
        for (int mt = 0; mt < 2; mt++) {
            v8bf af[4];
            #pragma unroll
            for (int kk = 0; kk < 4; kk++)
                af[kk] = *(const v8bf*)&Olds[(mt * 16 + l15) * 136 + kk * 32 + lg * 8];
            #pragma unroll
            for (int n2 = 0; n2 < 2; n2++)
                #pragma unroll
                for (int kk = 0; kk < 4; kk++)
                    po[mt][n2] = MFMA(af[kk], wf[n2][kk], po[mt][n2]);
        }

        #pragma unroll
        for (int mt = 0; mt < 2; mt++)
            #pragma unroll
            for (int n2 = 0; n2 < 2; n2++)
                #pragma unroll
                for (int ri = 0; ri < 4; ri++) {
                    const int row = ch * 32 + mt * 16 + lg * 4 + ri;
                    if (row < 125)
                        out[((size_t)s * 256000 + (size_t)b * 125 + row) * 128
                            + hv * 32 + n2 * 16 + l15] = po[mt][n2][ri] + bpv[n2];
                }
        __syncthreads();
    }
}

// =================== SLOW PATH (round-3 validated fallback) ===================

__global__ __launch_bounds__(64) void fused_attn(
    const void* __restrict__ x, const void* __restrict__ y,
    const void* __restrict__ maskx, const void* __restrict__ masky,
    const void* __restrict__ wqkvx, const void* __restrict__ bqkvx,
    const void* __restrict__ wqkvy, const void* __restrict__ bqkvy,
    const void* __restrict__ rpb, const int* __restrict__ flag,
    float* __restrict__ out)
{
    const bool f32 = (*flag != 0);
    const int b = blockIdx.x >> 1;
    const int s = blockIdx.x & 1;
    const int h = blockIdx.y;
    const int lane = threadIdx.x;
    const int l15 = lane & 15, lg = lane >> 4;

    __shared__ u16 QL[125][40];
    __shared__ u16 KL[125][40];
    __shared__ u16 VT[32][136];
    __shared__ u16 P[32][136];

    const void* inS = s ? y : x;
    const void* inO = s ? x : y;
    const void* wS  = s ? wqkvy : wqkvx;
    const void* wO  = s ? wqkvx : wqkvy;
    const void* bS  = s ? bqkvy : bqkvx;
    const void* bO  = s ? bqkvx : bqkvy;
    const void* msk = s ? masky : maskx;

    const size_t inb = (size_t)b * (125 * 128);

    #pragma unroll
    for (int t = 0; t < 3; t++) {
        const void* src = t ? inO : inS;
        const void* wp  = t ? wO  : wS;
        const void* bp  = t ? bO  : bS;
        const int wrow = t * 128 + h * 32;

        v8bf bfr[2][4];
        float bv[2];
        #pragma unroll
        for (int nt = 0; nt < 2; nt++) {
            bv[nt] = load1(bp, wrow + nt * 16 + l15, f32);
            #pragma unroll
            for (int kk = 0; kk < 4; kk++)
                bfr[nt][kk] = load8(wp, (size_t)(wrow + nt * 16 + l15) * 128 + kk * 32 + lg * 8, f32);
        }
        #pragma unroll
        for (int mt = 0; mt < 8; mt++) {
            int ar = mt * 16 + l15; if (ar > 124) ar = 124;
            v8bf af[4];
            #pragma unroll
            for (int kk = 0; kk < 4; kk++)
                af[kk] = load8(src, inb + (size_t)ar * 128 + kk * 32 + lg * 8, f32);
            v4f a0 = {0.f,0.f,0.f,0.f}, a1 = {0.f,0.f,0.f,0.f};
            #pragma unroll
            for (int kk = 0; kk < 4; kk++) {
                a0 = MFMA(af[kk], bfr[0][kk], a0);
                a1 = MFMA(af[kk], bfr[1][kk], a1);
            }
            #pragma unroll
            for (int nt = 0; nt < 2; nt++) {
                const v4f acc = nt ? a1 : a0;
                const int col = nt * 16 + l15;
                #pragma unroll
                for (int ri = 0; ri < 4; ri++) {
                    const int wr = mt * 16 + lg * 4 + ri;
                    if (wr < 125) {
                        const u16 val = f2bf(acc[ri] + bv[nt]);
                        if (t == 0)      QL[wr][col] = val;
                        else if (t == 1) KL[wr][col] = val;
                        else             VT[col][wr] = val;
                    }
                }
            }
        }
    }
    for (int z = lane; z < 96; z += 64) VT[z & 31][125 + (z >> 5)] = 0;
    __syncthreads();

    v8bf kf[8];
    #pragma unroll
    for (int jt = 0; jt < 8; jt++) {
        int r = jt * 16 + l15; if (r > 124) r = 124;
        kf[jt] = *(const v8bf*)&KL[r][lg * 8];
    }
    v8bf vf[2][4];
    #pragma unroll
    for (int n2 = 0; n2 < 2; n2++)
        #pragma unroll
        for (int kk = 0; kk < 4; kk++)
            vf[n2][kk] = *(const v8bf*)&VT[n2 * 16 + l15][kk * 32 + lg * 8];

    int cb[8];
    #pragma unroll
    for (int jt = 0; jt < 8; jt++) {
        int col = jt * 16 + l15; if (col > 124) col = 124;
        const int q0 = col / 25, rem = col - q0 * 25, q1 = rem / 5, q2 = rem - q1 * 5;
        cb[jt] = 364 - (q0 * 81 + q1 * 9 + q2);
    }
    const size_t mbase = (size_t)(b & 255) * 15625;
    const float scale = 0.17677669529663689f;
    const v4f z4 = {0.f,0.f,0.f,0.f};

    for (int ch = 0; ch < 4; ch++) {
        v8bf qf[2];
        #pragma unroll
        for (int mt = 0; mt < 2; mt++) {
            int r = ch * 32 + mt * 16 + l15; if (r > 124) r = 124;
            qf[mt] = *(const v8bf*)&QL[r][lg * 8];
        }
        v4f acc[2][8];
        #pragma unroll
        for (int mt = 0; mt < 2; mt++)
            #pragma unroll
            for (int jt = 0; jt < 8; jt++) acc[mt][jt] = z4;
        #pragma unroll
        for (int jt = 0; jt < 8; jt++)
            #pragma unroll
            for (int mt = 0; mt < 2; mt++)
                acc[mt][jt] = MFMA(qf[mt], kf[jt], acc[mt][jt]);

        float rinv[2][4];
        #pragma unroll
        for (int mt = 0; mt < 2; mt++) {
            #pragma unroll
            for (int ri = 0; ri < 4; ri++) {
                const int row = ch * 32 + mt * 16 + lg * 4 + ri;
                const bool rv = row < 125;
                int prow = 0; size_t moff = 0;
                if (rv) {
                    const int p0 = row / 25, rem = row - p0 * 25, p1 = rem / 5, p2 = rem - p1 * 5;
                    prow = p0 * 81 + p1 * 9 + p2;
                    moff = mbase + (size_t)row * 125;
                }
                #pragma unroll
                for (int jt = 0; jt < 8; jt++) {
                    const int col = jt * 16 + l15;
                    float vv = -1e30f;
                    if (rv && col < 125)
                        vv = acc[mt][jt][ri] * scale
                           + load1(rpb, (size_t)(prow + cb[jt]) * 4 + h, f32)
                           + load1(msk, moff + col, f32);
                    acc[mt][jt][ri] = vv;
                }
                float mx = acc[mt][0][ri];
                #pragma unroll
                for (int jt = 1; jt < 8; jt++) mx = fmaxf(mx, acc[mt][jt][ri]);
                mx = fmaxf(mx, __shfl_xor(mx, 1));
                mx = fmaxf(mx, __shfl_xor(mx, 2));
                mx = fmaxf(mx, __shfl_xor(mx, 4));
                mx = fmaxf(mx, __shfl_xor(mx, 8));
                float sum = 0.f;
                #pragma unroll
                for (int jt = 0; jt < 8; jt++) {
                    const float pv = __expf(acc[mt][jt][ri] - mx);
                    acc[mt][jt][ri] = pv; sum += pv;
                }
                sum += __shfl_xor(sum, 1);
                sum += __shfl_xor(sum, 2);
                sum += __shfl_xor(sum, 4);
                sum += __shfl_xor(sum, 8);
                rinv[mt][ri] = 1.0f / sum;
            }
        }

        __syncthreads();
        #pragma unroll
        for (int mt = 0; mt < 2; mt++)
            #pragma unroll
            for (int jt = 0; jt < 8; jt++)
                #pragma unroll
                for (int ri = 0; ri < 4; ri++)
                    P[mt * 16 + lg * 4 + ri][jt * 16 + l15] = f2bf(acc[mt][jt][ri]);
        __syncthreads();

        v4f o[2][2];
        #pragma unroll
        for (int mt = 0; mt < 2; mt++)
            #pragma unroll
            for (int n2 = 0; n2 < 2; n2++) o[mt][n2] = z4;
        #pragma unroll
        for (int mt = 0; mt < 2; mt++) {
            v8bf pa[4];
            #pragma unroll
            for (int kk = 0; kk < 4; kk++)
                pa[kk] = *(const v8bf*)&P[mt * 16 + l15][kk * 32 + lg * 8];
            #pragma unroll
            for (int n2 = 0; n2 < 2; n2++)
                #pragma unroll
                for (int kk = 0; kk < 4; kk++)
                    o[mt][n2] = MFMA(pa[kk], vf[n2][kk], o[mt][n2]);
        }

        #pragma unroll
        for (int mt = 0; mt < 2; mt++)
            #pragma unroll
            for (int n2 = 0; n2 < 2; n2++)
                #pragma unroll
                for (int ri = 0; ri < 4; ri++) {
                    const int row = ch * 32 + mt * 16 + lg * 4 + ri;
                    if (row < 125)
                        out[((size_t)s * 256000 + (size_t)b * 125 + row) * 128
                            + h * 32 + n2 * 16 + l15] = o[mt][n2][ri] * rinv[mt][ri];
                }
    }
}

// ---- output projection, in place on fp32 d_out (fallback path only) ----
__global__ __launch_bounds__(256) void proj_kernel(
    const void* __restrict__ wpx, const void* __restrict__ bpx,
    const void* __restrict__ wpy, const void* __restrict__ bpy,
    const int* __restrict__ flag, float* io)
{
    const bool f32 = (*flag != 0);
    const int s  = blockIdx.y;
    const int bm = blockIdx.x;
    const void* W    = s ? wpy : wpx;
    const void* bias = s ? bpy : bpx;
    float* A = io + (size_t)s * 32768000;
    const int tid = threadIdx.x, lane = tid & 63, wv = tid >> 6;
    const int l15 = lane & 15, lg = lane >> 4;

    __shared__ u16 Wl[128][136];
    for (int i = tid * 8; i < 16384; i += 2048)
        *(v8bf*)&Wl[i >> 7][i & 127] = load8(W, i, f32);
    __syncthreads();

    const int mbase = bm * 64 + wv * 16;
    v4f acc[8];
    const v4f z4 = {0.f,0.f,0.f,0.f};
    #pragma unroll
    for (int nt = 0; nt < 8; nt++) acc[nt] = z4;

    const float* Ar = A + (size_t)(mbase + l15) * 128;
    v8bf afr[4];
    #pragma unroll
    for (int kk = 0; kk < 4; kk++) {
        union { u16 sI[8]; v8bf v; } U;
        float4 fa = *(const float4*)(Ar + kk * 32 + lg * 8);
        float4 fb = *(const float4*)(Ar + kk * 32 + lg * 8 + 4);
        U.sI[0] = f2bf(fa.x); U.sI[1] = f2bf(fa.y); U.sI[2] = f2bf(fa.z); U.sI[3] = f2bf(fa.w);
        U.sI[4] = f2bf(fb.x); U.sI[5] = f2bf(fb.y); U.sI[6] = f2bf(fb.z); U.sI[7] = f2bf(fb.w);
        afr[kk] = U.v;
    }
    #pragma unroll
    for (int kk = 0; kk < 4; kk++)
        #pragma unroll
        for (int nt = 0; nt < 8; nt++)
            acc[nt] = MFMA(afr[kk], *(const v8bf*)&Wl[nt * 16 + l15][kk * 32 + lg * 8], acc[nt]);

    #pragma unroll
    for (int nt = 0; nt < 8; nt++) {
        const int c = nt * 16 + l15;
        const float bv = load1(bias, c, f32);
        #pragma unroll
        for (int ri = 0; ri < 4; ri++)
            A[(size_t)(mbase + lg * 4 + ri) * 128 + c] = acc[nt][ri] + bv;
    }
}

extern "C" void kernel_launch(void* const* d_in, const int* in_sizes, int n_in,
                              void* d_out, int out_size, void* d_ws, size_t ws_size,
                              hipStream_t stream) {
    const float* x     = (const float*)d_in[0];
    const float* y     = (const float*)d_in[1];
    const float* maskx = (const float*)d_in[2];
    const float* masky = (const float*)d_in[3];
    const float* wqx   = (const float*)d_in[4];
    const float* bqx   = (const float*)d_in[5];
    const float* wqy   = (const float*)d_in[6];
    const float* bqy   = (const float*)d_in[7];
    const float* wpx   = (const float*)d_in[8];
    const float* bpx   = (const float*)d_in[9];
    const float* wpy   = (const float*)d_in[10];
    const float* bpy   = (const float*)d_in[11];
    const float* rpb   = (const float*)d_in[12];

    const size_t OFF_R0   = 0;
    const size_t OFF_Q    = 256000;
    const size_t OFF_K    = OFF_Q + 131072000;
    const size_t OFF_VT   = OFF_K + 131072000;
    const size_t OFF_WP   = OFF_VT + 134217728;
    const size_t OFF_BP   = OFF_WP + 65536;
    const size_t OFF_FLAG = OFF_BP + 512;
    const size_t NEED_MID = OFF_FLAG + 4;
    const size_t OFF_MT   = (NEED_MID + 15) & ~(size_t)15;
    const size_t NEED_BIG = OFF_MT + 32768000;                // 429,451,792
    const size_t OFF_RP   = NEED_BIG;
    const size_t NEED_BIG2 = OFF_RP + 256000;                 // 429,707,792
    const size_t OFF_CMB  = (NEED_BIG2 + 15) & ~(size_t)15;
    const size_t NEED_CMB = OFF_CMB + 131072000;              // ~560.8 MB (proven r18/r19)

    if (ws_size >= NEED_MID) {
        u16*   wb   = (u16*)((char*)d_ws + OFF_R0);
        u16*   bb   = wb + 98304;
        float* rpbR = (float*)((char*)d_ws + OFF_R0);   // region0 phase 2 (tiers B/C)
        u16*   q    = (u16*)((char*)d_ws + OFF_Q);
        u16*   k    = (u16*)((char*)d_ws + OFF_K);
        u16*   vT   = (u16*)((char*)d_ws + OFF_VT);
        u16*   wpb  = (u16*)((char*)d_ws + OFF_WP);
        u16*   bpb  = (u16*)((char*)d_ws + OFF_BP);

        wconv_kernel<<<dim3(256, 2), 256, 0, stream>>>(wqx, bqx, wqy, bqy,
                                                       wpx, bpx, wpy, bpy,
                                                       wb, bb, wpb, bpb);
        if (ws_size >= NEED_CMB) {
            // tier D: r18 gather cmb (proven) + interleaved block roles
            float* cmbT = (float*)((char*)d_ws + OFF_CMB);
            qkvc_kernel<<<dim3(2048, 2), 256, 0, stream>>>(x, y, wb, bb,
                                                           maskx, masky, rpb,
                                                           q, k, vT, cmbT);
            attn_cmb<<<4096, 256, 0, stream>>>(q, k, vT, cmbT,
                                               wpb, bpb, (float*)d_out);
        } else if (ws_size >= NEED_BIG2) {
            // tier A: r17 proven path
            float* mskP = (float*)((char*)d_ws + OFF_MT);
            float* rpbP = (float*)((char*)d_ws + OFF_RP);
            qkvt_kernel<<<dim3(1282, 2), 256, 0, stream>>>(x, y, wb, bb,
                                                           maskx, masky, rpb,
                                                           q, k, vT, mskP, rpbP);
            attn_swp<<<4096, 256, 0, stream>>>(q, k, vT, mskP, rpbP,
                                               wpb, bpb, (float*)d_out);
        } else if (ws_size >= NEED_BIG) {
            // tier B: split launches
            float* mskP = (float*)((char*)d_ws + OFF_MT);
            qkv_kernel<<<dim3(1024, 2), 256, 0, stream>>>(x, y, wb, bb, q, k, vT);
            rpbp_kernel<<<4, 256, 0, stream>>>(rpb, rpbR);       // overwrites wb/bb
            mskp_kernel<<<dim3(256, 2), 256, 0, stream>>>(maskx, masky, mskP);
            attn_swp<<<4096, 256, 0, stream>>>(q, k, vT, mskP, rpbR,
                                               wpb, bpb, (float*)d_out);
        } else {
            // tier C: mid (mask staged in LDS)
            qkv_kernel<<<dim3(1024, 2), 256, 0, stream>>>(x, y, wb, bb, q, k, vT);
            rpbt_kernel<<<4, 256, 0, stream>>>(rpb, rpbR);       // col-major
            attn_mld_kernel<<<4096, 256, 0, stream>>>(q, k, vT, maskx, masky, rpbR,
                                                      wpb, bpb, (float*)d_out);
        }
    } else {
        int* flag = (int*)d_ws;
        probe_kernel<<<1, 64, 0, stream>>>((const unsigned*)x, flag);
        fused_attn<<<dim3(4096, 4), 64, 0, stream>>>(x, y, maskx, masky,
                                                     wqx, bqx, wqy, bqy,
                                                     rpb, flag, (float*)d_out);
        proj_kernel<<<dim3(4000, 2), 256, 0, stream>>>(wpx, bpx, wpy, bpy,
                                                       flag, (float*)d_out);
    }
}

// Round 21
// 554.495 us; speedup vs baseline: 1.1673x; 1.1673x over previous
//
#include <hip/hip_runtime.h>
#include <stdint.h>

typedef unsigned short u16;                                   // raw bf16 bits
typedef __bf16 v8bf __attribute__((ext_vector_type(8)));      // MFMA A/B frag
typedef float  v4f  __attribute__((ext_vector_type(4)));      // MFMA C/D frag
typedef u16    u16x4 __attribute__((ext_vector_type(4)));

#define MFMA(a,b,c) __builtin_amdgcn_mfma_f32_16x16x32_bf16((a),(b),(c),0,0,0)
#define LOG2E 1.4426950408889634f

static __device__ __forceinline__ float bf2f(u16 u) {
    union { unsigned i; float f; } v; v.i = ((unsigned)u) << 16; return v.f;
}
static __device__ __forceinline__ u16 f2bf(float f) {         // RNE (manual)
    union { float f; unsigned i; } v; v.f = f;
    unsigned u = v.i;
    return (u16)((u + 0x7FFFu + ((u >> 16) & 1u)) >> 16);
}
static __device__ __forceinline__ u16 bfc(float f) {          // RNE via HW cvt
    union { __bf16 h; u16 u; } c; c.h = (__bf16)f; return c.u;
}
// fp32 -> bf16 frag (8 elems)
static __device__ __forceinline__ v8bf load8f(const float* p) {
    union { u16 s[8]; v8bf v; } U;
    float4 a = *(const float4*)p;
    float4 b = *(const float4*)(p + 4);
    U.s[0] = bfc(a.x); U.s[1] = bfc(a.y); U.s[2] = bfc(a.z); U.s[3] = bfc(a.w);
    U.s[4] = bfc(b.x); U.s[5] = bfc(b.y); U.s[6] = bfc(b.z); U.s[7] = bfc(b.w);
    return U.v;
}
// dual-dtype helpers (slow path only)
static __device__ __forceinline__ v8bf load8(const void* base, size_t off, bool f32) {
    union { u16 s[8]; v8bf v; } U;
    if (f32) return load8f((const float*)base + off);
    U.v = *(const v8bf*)((const u16*)base + off);
    return U.v;
}
static __device__ __forceinline__ float load1(const void* base, size_t off, bool f32) {
    return f32 ? ((const float*)base)[off] : bf2f(((const u16*)base)[off]);
}

// ---- dtype probe (slow path only) ----
__global__ void probe_kernel(const unsigned* __restrict__ x, int* __restrict__ flag) {
    if (threadIdx.x == 0 && blockIdx.x == 0) {
        int b16like = 0;
        for (int i = 0; i < 128; i++) {
            unsigned lo = x[i] & 0xFFFFu;
            int e = (lo >> 7) & 0xFF;
            if (e >= 110 && e <= 140) b16like++;
        }
        *flag = (b16like >= 64) ? 0 : 1;   // 1 => fp32 inputs
    }
}

// =================== FAST PATH (fp32 inputs, uses workspace) ===================

// ---- K0: convert qkv + proj weights/biases to bf16. grid (256, 2) ----
__global__ __launch_bounds__(256) void wconv_kernel(
    const float* __restrict__ wqkvx, const float* __restrict__ bqkvx,
    const float* __restrict__ wqkvy, const float* __restrict__ bqkvy,
    const float* __restrict__ wpx, const float* __restrict__ bpx,
    const float* __restrict__ wpy, const float* __restrict__ bpy,
    u16* __restrict__ wb, u16* __restrict__ bb,
    u16* __restrict__ wpb, u16* __restrict__ bpb)
{
    const int s = blockIdx.y;
    const int i = blockIdx.x * 256 + threadIdx.x;      // [0, 65536)
    if (i < 49152) {
        wb[(size_t)s * 49152 + i] = bfc((s ? wqkvy : wqkvx)[i]);
    } else {
        wpb[(size_t)s * 16384 + (i - 49152)] = bfc((s ? wpy : wpx)[i - 49152]);
    }
    if (i < 384)       bb[s * 384 + i]          = bfc((s ? bqkvy : bqkvx)[i]);
    else if (i < 512)  bpb[s * 128 + (i - 384)] = bfc((s ? bpy : bpx)[i - 384]);
}

// ---- device bodies shared by mega + standalone kernels ----
static __device__ __forceinline__ void mask_body(
    int w, int s, const float* maskx, const float* masky, float* mskP, int tid)
{
    const float* m = s ? masky : maskx;
    const size_t base = (size_t)w * 15625;
    float* dst = mskP + ((size_t)s * 256 + w) * 16000;
    for (int i = tid; i < 16000; i += 256) {
        const int row = i >> 7;
        int col = i & 127; if (col > 124) col = 124;
        dst[i] = m[base + (size_t)row * 125 + col] * LOG2E;
    }
}
static __device__ __forceinline__ void rpb_body(
    int h, const float* rpb, float* rpbP, int tid)
{
    for (int i = tid; i < 16000; i += 256) {
        const int row = i >> 7;                   // query (< 125)
        int col = i & 127; if (col > 124) col = 124;
        const int p0 = row / 25, prem = row - p0 * 25, p1 = prem / 5, p2 = prem - p1 * 5;
        const int q0 = col / 25, qrem = col - q0 * 25, q1 = qrem / 5, q2 = qrem - q1 * 5;
        const int idx = (p0 - q0 + 4) * 81 + (p1 - q1 + 4) * 9 + (p2 - q2 + 4);
        rpbP[(size_t)h * 16000 + i] = rpb[(size_t)idx * 4 + h] * LOG2E;
    }
}
// combined (mask + rpb) * LOG2E table (gather form; rpb is L1-resident 6KB)
static __device__ __forceinline__ void cmb_body(
    int w, int h, int s, const float* maskx, const float* masky,
    const float* rpb, float* cmb, int tid)
{
    const float* m = s ? masky : maskx;
    const size_t mbase = (size_t)w * 15625;
    float* dst = cmb + (((size_t)s * 256 + w) * 4 + h) * 16000;
    for (int i = tid; i < 16000; i += 256) {
        const int row = i >> 7;
        int col = i & 127; if (col > 124) col = 124;
        const int p0 = row / 25, prem = row - p0 * 25, p1 = prem / 5, p2 = prem - p1 * 5;
        const int q0 = col / 25, qrem = col - q0 * 25, q1 = qrem / 5, q2 = qrem - q1 * 5;
        const int idx = (p0 - q0 + 4) * 81 + (p1 - q1 + 4) * 9 + (p2 - q2 + 4);
        dst[i] = (m[mbase + (size_t)row * 125 + col] + rpb[(size_t)idx * 4 + h]) * LOG2E;
    }
}
// 256 tokens per block (64/wave, mt=0..3): weight fragments amortized 2x
static __device__ __forceinline__ void qkv_body(
    int mblk, int s, const float* x, const float* y,
    const u16* wb, const u16* bb,
    u16* q, u16* k, u16* vT, int tid)
{
    const float* A = s ? y : x;
    const u16* W  = wb + (size_t)s * 49152;
    const u16* Bb = bb + s * 384;
    const int lane = tid & 63, wv = tid >> 6;
    const int l15 = lane & 15, lg = lane >> 4;

    const int mbase = mblk * 256 + wv * 64;          // padded-m space [0, 262144)

    v8bf af[4][4];
    #pragma unroll
    for (int mt = 0; mt < 4; mt++) {
        const int mr = mbase + mt * 16 + l15;
        const int b  = mr >> 7;
        int n = mr & 127; if (n > 124) n = 124;      // clamp pad rows
        const float* arow = A + (size_t)(b * 125 + n) * 128;
        #pragma unroll
        for (int kk = 0; kk < 4; kk++)
            af[mt][kk] = load8f(arow + kk * 32 + lg * 8);
    }

    const v4f z4 = {0.f,0.f,0.f,0.f};
    #pragma unroll
    for (int nt = 0; nt < 24; nt++) {
        const int col0 = nt * 16;
        v8bf bfr[4];
        #pragma unroll
        for (int kk = 0; kk < 4; kk++)
            bfr[kk] = *(const v8bf*)(W + (size_t)(col0 + l15) * 128 + kk * 32 + lg * 8);

        const int three = col0 >> 7;                 // 0=q 1=k 2=v
        const int h     = (col0 >> 5) & 3;

        if (three < 2) {
            // q/k: SWAPPED MFMA -> D[channel][token]; packed u16x4 stores
            float bv[4];
            {
                const u16x4 bq = *(const u16x4*)&Bb[col0 + 4 * lg];
                #pragma unroll
                for (int r = 0; r < 4; r++) bv[r] = bf2f(bq[r]);
            }
            u16* dst = (three == 0) ? q : k;
            const int d0 = (col0 & 31) + 4 * lg;
            #pragma unroll
            for (int mt = 0; mt < 4; mt++) {
                v4f a0 = z4;
                #pragma unroll
                for (int kk = 0; kk < 4; kk++)
                    a0 = MFMA(bfr[kk], af[mt][kk], a0);
                const int t = mbase + mt * 16 + l15;
                const int b = t >> 7;
                int n = t & 127; if (n > 124) n = 124;   // dup-write same value
                const size_t hb = (size_t)(s * 2048 + b) * 4 + h;
                u16x4 pk;
                #pragma unroll
                for (int ri = 0; ri < 4; ri++) pk[ri] = bfc(a0[ri] + bv[ri]);
                *(u16x4*)&dst[hb * 4000 + n * 32 + d0] = pk;
            }
        } else {
            // v: unswapped -> vT packed store
            const float bv = bf2f(Bb[col0 + l15]);
            const int d = (col0 & 31) + l15;
            #pragma unroll
            for (int mt = 0; mt < 4; mt++) {
                v4f a0 = z4;
                #pragma unroll
                for (int kk = 0; kk < 4; kk++)
                    a0 = MFMA(af[mt][kk], bfr[kk], a0);
                const int m0 = mbase + mt * 16 + lg * 4;
                const int b  = m0 >> 7;
                const int n0 = m0 & 127;
                const size_t hb = (size_t)(s * 2048 + b) * 4 + h;
                u16x4 pk;
                #pragma unroll
                for (int ri = 0; ri < 4; ri++) pk[ri] = bfc(a0[ri] + bv);
                *(u16x4*)&vT[hb * 4096 + (size_t)d * 128 + n0] = pk;
            }
        }
    }
}

// ---- K2c (tier D): fused qkv + combined-table builder. grid (2048, 2).
// SEQUENTIAL roles (r18 proven): bx<1024 table slices, then qkv tiles. ----
__global__ __launch_bounds__(256) void qkvc_kernel(
    const float* __restrict__ x, const float* __restrict__ y,
    const u16* __restrict__ wb, const u16* __restrict__ bb,
    const float* __restrict__ maskx, const float* __restrict__ masky,
    const float* __restrict__ rpb,
    u16* __restrict__ q, u16* __restrict__ k, u16* __restrict__ vT,
    float* __restrict__ cmb)
{
    const int bx = blockIdx.x, by = blockIdx.y, tid = threadIdx.x;
    if (bx < 1024) cmb_body(bx >> 2, bx & 3, by, maskx, masky, rpb, cmb, tid);
    else           qkv_body(bx - 1024, by, x, y, wb, bb, q, k, vT, tid);
}

// ---- K2a (tier A): fused qkv + split table builders. grid (1282, 2) ----
__global__ __launch_bounds__(256) void qkvt_kernel(
    const float* __restrict__ x, const float* __restrict__ y,
    const u16* __restrict__ wb, const u16* __restrict__ bb,
    const float* __restrict__ maskx, const float* __restrict__ masky,
    const float* __restrict__ rpb,
    u16* __restrict__ q, u16* __restrict__ k, u16* __restrict__ vT,
    float* __restrict__ mskP, float* __restrict__ rpbP)
{
    const int bx = blockIdx.x, by = blockIdx.y, tid = threadIdx.x;
    if (bx < 256)       mask_body(bx, by, maskx, masky, mskP, tid);
    else if (bx < 258)  rpb_body((bx - 256) * 2 + by, rpb, rpbP, tid);
    else                qkv_body(bx - 258, by, x, y, wb, bb, q, k, vT, tid);
}

// ---- K2b (tier B/C): standalone qkv. grid (1024, 2) ----
__global__ __launch_bounds__(256) void qkv_kernel(
    const float* __restrict__ x, const float* __restrict__ y,
    const u16* __restrict__ wb, const u16* __restrict__ bb,
    u16* __restrict__ q, u16* __restrict__ k, u16* __restrict__ vT)
{
    qkv_body(blockIdx.x, blockIdx.y, x, y, wb, bb, q, k, vT, threadIdx.x);
}

// ---- standalone table kernels ----
__global__ __launch_bounds__(256) void mskp_kernel(
    const float* __restrict__ maskx, const float* __restrict__ masky,
    float* __restrict__ mskP)
{
    mask_body(blockIdx.x, blockIdx.y, maskx, masky, mskP, threadIdx.x);
}
__global__ __launch_bounds__(256) void rpbp_kernel(
    const float* __restrict__ rpb, float* __restrict__ rpbP)
{
    rpb_body(blockIdx.x, rpb, rpbP, threadIdx.x);
}

// ---- K1 (mid tier): rpbT[h][col(key)][row(query) pad128] fp32 (col-major) ----
__global__ __launch_bounds__(256) void rpbt_kernel(
    const float* __restrict__ rpb, float* __restrict__ rpbT)
{
    const int h = blockIdx.x;
    for (int i = threadIdx.x; i < 16000; i += 256) {
        const int col = i >> 7, row = i & 127;
        float v = 0.f;
        if (row < 125) {
            const int p0 = row / 25, prem = row - p0 * 25, p1 = prem / 5, p2 = prem - p1 * 5;
            const int q0 = col / 25, qrem = col - q0 * 25, q1 = qrem / 5, q2 = qrem - q1 * 5;
            const int idx = (p0 - q0 + 4) * 81 + (p1 - q1 + 4) * 9 + (p2 - q2 + 4);
            v = rpb[(size_t)idx * 4 + h];
        }
        rpbT[(size_t)h * 16000 + i] = v;
    }
}

// ---- K3 (tier D): attn with COMBINED table (frozen r18 form, ~240 us) ----
__global__ __launch_bounds__(256) void attn_cmb(
    const u16* __restrict__ q, const u16* __restrict__ k, const u16* __restrict__ vT,
    const float* __restrict__ cmb,
    const u16* __restrict__ wpb, const u16* __restrict__ bpb,
    float* __restrict__ out)
{
    const int bid = blockIdx.x;                    // 4096 = 8 xcd * 512
    const int rep = (bid >> 3) & 15;               // same-w blocks -> same XCD
    const int w   = ((bid >> 7) << 3) | (bid & 7);
    const int s = rep & 1, b = (rep >> 1) * 256 + w;
    const int tid = threadIdx.x;
    const int hv = tid >> 6;                       // wave = head
    const int lane = tid & 63, l15 = lane & 15, lg = lane >> 4;

    __shared__ u16 Pl[4][16][140];                 // per-wave P^T slab (17920 B)
    __shared__ u16 Olds[32][136];                  // shared O tile (8704 B)
    u16* P = &Pl[hv][0][0];

    const u16* qb = q  + ((size_t)(s * 2048 + b) * 4 + hv) * 4000;
    const u16* kb = k  + ((size_t)((1 - s) * 2048 + b) * 4 + hv) * 4000;
    const u16* vb = vT + ((size_t)((1 - s) * 2048 + b) * 4 + hv) * 4096;
    const float* tP = cmb + (((size_t)s * 256 + w) * 4 + hv) * 16000;
    const u16* Wp = wpb + (size_t)s * 16384;       // [c][d] bf16
    float bpv[2];
    #pragma unroll
    for (int n2 = 0; n2 < 2; n2++)
        bpv[n2] = bf2f(bpb[s * 128 + hv * 32 + n2 * 16 + l15]);

    v8bf kf[8];                                    // resident K frags (A-operand)
    #pragma unroll
    for (int jt = 0; jt < 8; jt++) {
        int c = jt * 16 + l15; if (c > 124) c = 124;
        kf[jt] = *(const v8bf*)(kb + c * 32 + lg * 8);
    }

    const float scale2 = 0.17677669529663689f * LOG2E;   // 32^-0.5 * log2(e)
    const v4f z4 = {0.f,0.f,0.f,0.f};

    for (int ch = 0; ch < 4; ch++) {
        v4f ot[2][2];                              // O^T accum [mt][n2]
        float rinv[2];

        #pragma unroll
        for (int mt = 0; mt < 2; mt++) {
            int qr = ch * 32 + mt * 16 + l15; if (qr > 124) qr = 124;
            const v8bf qf = *(const v8bf*)(qb + qr * 32 + lg * 8);

            v4f acc[8];
            #pragma unroll
            for (int jt = 0; jt < 8; jt++) acc[jt] = z4;
            #pragma unroll
            for (int jt = 0; jt < 8; jt++)
                acc[jt] = MFMA(kf[jt], qf, acc[jt]);   // SWAPPED: D[key][qrow]

            // combined bias+mask (log2-domain), ONE float4 per jt
            const float* trow = tP + (size_t)qr * 128 + 4 * lg;
            #pragma unroll
            for (int jt = 0; jt < 8; jt++) {
                const float4 tb4 = *(const float4*)(trow + jt * 16);
                #pragma unroll
                for (int ri = 0; ri < 4; ri++) {
                    float t = fmaf(acc[jt][ri], scale2, (&tb4.x)[ri]);
                    if (jt == 7) t = (4 * lg + ri < 13) ? t : -1e30f;  // key >= 125
                    acc[jt][ri] = t;
                }
            }

            // lane-local softmax (row = l15), 2-shfl reduce across lg groups
            float mx = acc[0][0];
            #pragma unroll
            for (int jt = 0; jt < 8; jt++)
                #pragma unroll
                for (int ri = 0; ri < 4; ri++) mx = fmaxf(mx, acc[jt][ri]);
            mx = fmaxf(mx, __shfl_xor(mx, 16));
            mx = fmaxf(mx, __shfl_xor(mx, 32));
            float sum = 0.f;
            #pragma unroll
            for (int jt = 0; jt < 8; jt++)
                #pragma unroll
                for (int ri = 0; ri < 4; ri++) {
                    const float pv = __builtin_amdgcn_exp2f(acc[jt][ri] - mx);
                    acc[jt][ri] = pv; sum += pv;
                }
            sum += __shfl_xor(sum, 16);
            sum += __shfl_xor(sum, 32);
            rinv[mt] = 1.0f / sum;                 // lane-scalar (qrow = l15)

            // pack P^T (bf16 pairs) into wave-local LDS: P[l15][key]
            #pragma unroll
            for (int jt = 0; jt < 8; jt++) {
                const int kb2 = jt * 16 + 4 * lg;
                const unsigned w0 = (unsigned)f2bf(acc[jt][0]) | ((unsigned)f2bf(acc[jt][1]) << 16);
                const unsigned w1 = (unsigned)f2bf(acc[jt][2]) | ((unsigned)f2bf(acc[jt][3]) << 16);
                *(unsigned*)&P[l15 * 140 + kb2]     = w0;
                *(unsigned*)&P[l15 * 140 + kb2 + 2] = w1;
            }

            // PV swapped: A = V^T frag (vT natural layout), B = P^T frag
            ot[mt][0] = z4; ot[mt][1] = z4;
            #pragma unroll
            for (int kk = 0; kk < 4; kk++) {
                const v8bf pb = *(const v8bf*)&P[l15 * 140 + kk * 32 + lg * 8];
                #pragma unroll
                for (int n2 = 0; n2 < 2; n2++) {
                    const v8bf va = *(const v8bf*)(vb + (n2 * 16 + l15) * 128 + kk * 32 + lg * 8);
                    ot[mt][n2] = MFMA(va, pb, ot[mt][n2]);
                }
            }
        }

        __syncthreads();                           // prior proj reads of Olds done
        // O^T -> Olds[chunk row][channel], rinv folded (lane-scalar), packed b32
        #pragma unroll
        for (int mt = 0; mt < 2; mt++)
            #pragma unroll
            for (int n2 = 0; n2 < 2; n2++) {
                const int row = mt * 16 + l15;
                const int col = hv * 32 + n2 * 16 + 4 * lg;
                const unsigned w0 = (unsigned)f2bf(ot[mt][n2][0] * rinv[mt])
                                  | ((unsigned)f2bf(ot[mt][n2][1] * rinv[mt]) << 16);
                const unsigned w1 = (unsigned)f2bf(ot[mt][n2][2] * rinv[mt])
                                  | ((unsigned)f2bf(ot[mt][n2][3] * rinv[mt]) << 16);
                *(unsigned*)&Olds[row][col]     = w0;
                *(unsigned*)&Olds[row][col + 2] = w1;
            }
        __syncthreads();                           // O tile complete

        // ---- fused projection: this wave's 32 output cols ----
        v8bf wf[2][4];
        #pragma unroll
        for (int n2 = 0; n2 < 2; n2++)
            #pragma unroll
            for (int kk = 0; kk < 4; kk++)
                wf[n2][kk] = *(const v8bf*)(Wp + (size_t)(hv * 32 + n2 * 16 + l15) * 128
                                            + kk * 32 + lg * 8);
        v4f po[2][2];
        #pragma unroll
        for (int mt = 0; mt < 2; mt++)
            #pragma unroll
            for (int n2 = 0; n2 < 2; n2++) po[mt][n2] = z4;
        #pragma unroll
        for (int mt = 0; mt < 2; mt++) {
            v8bf af[4];
            #pragma unroll
            for (int kk = 0; kk < 4; kk++)
                af[kk] = *(const v8bf*)&Olds[mt * 16 + l15][kk * 32 + lg * 8];
            #pragma unroll
            for (int n2 = 0; n2 < 2; n2++)
                #pragma unroll
                for (int kk = 0; kk < 4; kk++)
                    po[mt][n2] = MFMA(af[kk], wf[n2][kk], po[mt][n2]);
        }

        #pragma unroll
        for (int mt = 0; mt < 2; mt++)
            #pragma unroll
            for (int n2 = 0; n2 < 2; n2++)
                #pragma unroll
                for (int ri = 0; ri < 4; ri++) {
                    const int row = ch * 32 + mt * 16 + lg * 4 + ri;
                    if (row < 125)
                        out[((size_t)s * 256000 + (size_t)b * 125 + row) * 128
                            + hv * 32 + n2 * 16 + l15] = po[mt][n2][ri] + bpv[n2];
                }
        __syncthreads();                           // proj reads done before next chunk
    }
}

// ---- K3 (tiers A/B): EXACT r13/r15 frozen attn ----
__global__ __launch_bounds__(256) void attn_swp(
    const u16* __restrict__ q, const u16* __restrict__ k, const u16* __restrict__ vT,
    const float* __restrict__ mskP, const float* __restrict__ rpbP,
    const u16* __restrict__ wpb, const u16* __restrict__ bpb,
    float* __restrict__ out)
{
    const int bid = blockIdx.x;
    const int rep = (bid >> 3) & 15;
    const int w   = ((bid >> 7) << 3) | (bid & 7);
    const int s = rep & 1, b = (rep >> 1) * 256 + w;
    const int tid = threadIdx.x;
    const int hv = tid >> 6;
    const int lane = tid & 63, l15 = lane & 15, lg = lane >> 4;

    __shared__ u16 Pl[4][16][140];
    __shared__ u16 Olds[32][136];
    u16* P = &Pl[hv][0][0];

    const u16* qb = q  + ((size_t)(s * 2048 + b) * 4 + hv) * 4000;
    const u16* kb = k  + ((size_t)((1 - s) * 2048 + b) * 4 + hv) * 4000;
    const u16* vb = vT + ((size_t)((1 - s) * 2048 + b) * 4 + hv) * 4096;
    const float* mP = mskP + ((size_t)s * 256 + w) * 16000;
    const float* rP = rpbP + (size_t)hv * 16000;
    const u16* Wp = wpb + (size_t)s * 16384;
    float bpv[2];
    #pragma unroll
    for (int n2 = 0; n2 < 2; n2++)
        bpv[n2] = bf2f(bpb[s * 128 + hv * 32 + n2 * 16 + l15]);

    v8bf kf[8];
    #pragma unroll
    for (int jt = 0; jt < 8; jt++) {
        int c = jt * 16 + l15; if (c > 124) c = 124;
        kf[jt] = *(const v8bf*)(kb + c * 32 + lg * 8);
    }

    const float scale2 = 0.17677669529663689f * LOG2E;
    const v4f z4 = {0.f,0.f,0.f,0.f};

    for (int ch = 0; ch < 4; ch++) {
        v4f ot[2][2];
        float rinv[2];

        #pragma unroll
        for (int mt = 0; mt < 2; mt++) {
            int qr = ch * 32 + mt * 16 + l15; if (qr > 124) qr = 124;
            const v8bf qf = *(const v8bf*)(qb + qr * 32 + lg * 8);

            v4f acc[8];
            #pragma unroll
            for (int jt = 0; jt < 8; jt++) acc[jt] = z4;
            #pragma unroll
            for (int jt = 0; jt < 8; jt++)
                acc[jt] = MFMA(kf[jt], qf, acc[jt]);

            const float* rrow = rP + (size_t)qr * 128 + 4 * lg;
            const float* mrow = mP + (size_t)qr * 128 + 4 * lg;
            #pragma unroll
            for (int jt = 0; jt < 8; jt++) {
                const float4 rb4 = *(const float4*)(rrow + jt * 16);
                const float4 mv4 = *(const float4*)(mrow + jt * 16);
                #pragma unroll
                for (int ri = 0; ri < 4; ri++) {
                    float t = fmaf(acc[jt][ri], scale2, (&rb4.x)[ri] + (&mv4.x)[ri]);
                    if (jt == 7) t = (4 * lg + ri < 13) ? t : -1e30f;
                    acc[jt][ri] = t;
                }
            }

            float mx = acc[0][0];
            #pragma unroll
            for (int jt = 0; jt < 8; jt++)
                #pragma unroll
                for (int ri = 0; ri < 4; ri++) mx = fmaxf(mx, acc[jt][ri]);
            mx = fmaxf(mx, __shfl_xor(mx, 16));
            mx = fmaxf(mx, __shfl_xor(mx, 32));
            float sum = 0.f;
            #pragma unroll
            for (int jt = 0; jt < 8; jt++)
                #pragma unroll
                for (int ri = 0; ri < 4; ri++) {
                    const float pv = __builtin_amdgcn_exp2f(acc[jt][ri] - mx);
                    acc[jt][ri] = pv; sum += pv;
                }
            sum += __shfl_xor(sum, 16);
            sum += __shfl_xor(sum, 32);
            rinv[mt] = 1.0f / sum;

            #pragma unroll
            for (int jt = 0; jt < 8; jt++) {
                const int kb2 = jt * 16 + 4 * lg;
                const unsigned w0 = (unsigned)f2bf(acc[jt][0]) | ((unsigned)f2bf(acc[jt][1]) << 16);
                const unsigned w1 = (unsigned)f2bf(acc[jt][2]) | ((unsigned)f2bf(acc[jt][3]) << 16);
                *(unsigned*)&P[l15 * 140 + kb2]     = w0;
                *(unsigned*)&P[l15 * 140 + kb2 + 2] = w1;
            }

            ot[mt][0] = z4; ot[mt][1] = z4;
            #pragma unroll
            for (int kk = 0; kk < 4; kk++) {
                const v8bf pb = *(const v8bf*)&P[l15 * 140 + kk * 32 + lg * 8];
                #pragma unroll
                for (int n2 = 0; n2 < 2; n2++) {
                    const v8bf va = *(const v8bf*)(vb + (n2 * 16 + l15) * 128 + kk * 32 + lg * 8);
                    ot[mt][n2] = MFMA(va, pb, ot[mt][n2]);
                }
            }
        }

        __syncthreads();
        #pragma unroll
        for (int mt = 0; mt < 2; mt++)
            #pragma unroll
            for (int n2 = 0; n2 < 2; n2++) {
                const int row = mt * 16 + l15;
                const int col = hv * 32 + n2 * 16 + 4 * lg;
                const unsigned w0 = (unsigned)f2bf(ot[mt][n2][0] * rinv[mt])
                                  | ((unsigned)f2bf(ot[mt][n2][1] * rinv[mt]) << 16);
                const unsigned w1 = (unsigned)f2bf(ot[mt][n2][2] * rinv[mt])
                                  | ((unsigned)f2bf(ot[mt][n2][3] * rinv[mt]) << 16);
                *(unsigned*)&Olds[row][col]     = w0;
                *(unsigned*)&Olds[row][col + 2] = w1;
            }
        __syncthreads();

        v8bf wf[2][4];
        #pragma unroll
        for (int n2 = 0; n2 < 2; n2++)
            #pragma unroll
            for (int kk = 0; kk < 4; kk++)
                wf[n2][kk] = *(const v8bf*)(Wp + (size_t)(hv * 32 + n2 * 16 + l15) * 128
                                            + kk * 32 + lg * 8);
        v4f po[2][2];
        #pragma unroll
        for (int mt = 0; mt < 2; mt++)
            #pragma unroll
            for (int n2 = 0; n2 < 2; n2++) po[mt][n2] = z4;
        #pragma unroll
        for (int mt = 0; mt < 2; mt++) {
            v8bf af[4];
            #pragma unroll
            for (int kk = 0; kk < 4; kk++)
                af[kk] = *(const v8bf*)&Olds[mt * 16 + l15][kk * 32 + lg * 8];
            #pragma unroll
            for (int n2 = 0; n2 < 2; n2++)
                #pragma unroll
                for (int kk = 0; kk < 4; kk++)
                    po[mt][n2] = MFMA(af[kk], wf[n2][kk], po[mt][n2]);
        }

        #pragma unroll
        for (int mt = 0; mt < 2; mt++)
            #pragma unroll
            for (int n2 = 0; n2 < 2; n2++)
                #pragma unroll
                for (int ri = 0; ri < 4; ri++) {
                    const int row = ch * 32 + mt * 16 + lg * 4 + ri;
                    if (row < 125)
                        out[((size_t)s * 256000 + (size_t)b * 125 + row) * 128
                            + hv * 32 + n2 * 16 + l15] = po[mt][n2][ri] + bpv[n2];
                }
        __syncthreads();
    }
}

// ---- K3 (mid tier): round-8 validated kernel (mask staged in LDS), fp32 in ----
__global__ __launch_bounds__(256) void attn_mld_kernel(
    const u16* __restrict__ q, const u16* __restrict__ k, const u16* __restrict__ vT,
    const float* __restrict__ maskx, const float* __restrict__ masky,
    const float* __restrict__ rpbT,
    const u16* __restrict__ wpb, const u16* __restrict__ bpb,
    float* __restrict__ out)
{
    const int bid = blockIdx.x;
    const int rep = (bid >> 3) & 15;
    const int w   = ((bid >> 7) << 3) | (bid & 7);
    const int s = rep & 1, b = (rep >> 1) * 256 + w;
    const int tid = threadIdx.x;
    const int hv = tid >> 6;
    const int lane = tid & 63, l15 = lane & 15, lg = lane >> 4;

    __shared__ u16 Pb[4][32][136];
    __shared__ float Mld[32][132];
    u16* P    = &Pb[hv][0][0];
    u16* Olds = &Pb[0][0][0];

    const u16* qb = q  + ((size_t)(s * 2048 + b) * 4 + hv) * 4000;
    const u16* kb = k  + ((size_t)((1 - s) * 2048 + b) * 4 + hv) * 4000;
    const u16* vb = vT + ((size_t)((1 - s) * 2048 + b) * 4 + hv) * 4096;
    const float* msk = s ? masky : maskx;
    const size_t mbase = (size_t)w * 15625;
    const float* rT = rpbT + (size_t)hv * 16000;
    const u16* Wp = wpb + (size_t)s * 16384;
    float bpv[2];
    #pragma unroll
    for (int n2 = 0; n2 < 2; n2++)
        bpv[n2] = bf2f(bpb[s * 128 + hv * 32 + n2 * 16 + l15]);

    int colc[8];
    #pragma unroll
    for (int jt = 0; jt < 8; jt++) {
        int c = jt * 16 + l15; if (c > 124) c = 124;
        colc[jt] = c;
    }

    v8bf kf[8];
    #pragma unroll
    for (int jt = 0; jt < 8; jt++)
        kf[jt] = *(const v8bf*)(kb + colc[jt] * 32 + lg * 8);

    const float scale = 0.17677669529663689f;
    const v4f z4 = {0.f,0.f,0.f,0.f};

    for (int ch = 0; ch < 4; ch++) {
        for (int i = tid; i < 4096; i += 256) {
            const int r = i >> 7, c = i & 127;
            int rc = ch * 32 + r; if (rc > 124) rc = 124;
            int cc = c;          if (cc > 124) cc = 124;
            Mld[r][c] = msk[mbase + (size_t)rc * 125 + cc];
        }
        __syncthreads();

        float rinv[2][4];
        #pragma unroll
        for (int mt = 0; mt < 2; mt++) {
            int qr = ch * 32 + mt * 16 + l15; if (qr > 124) qr = 124;
            const v8bf qf = *(const v8bf*)(qb + qr * 32 + lg * 8);

            v4f acc[8];
            #pragma unroll
            for (int jt = 0; jt < 8; jt++) acc[jt] = z4;
            #pragma unroll
            for (int jt = 0; jt < 8; jt++)
                acc[jt] = MFMA(qf, kf[jt], acc[jt]);

            const int rloc = mt * 16 + lg * 4;
            const int rowb = ch * 32 + rloc;
            const bool tail = (ch == 3) && (mt == 1);

            #pragma unroll
            for (int jt = 0; jt < 8; jt++) {
                const float4 c4 = *(const float4*)(rT + colc[jt] * 128 + rowb);
                #pragma unroll
                for (int ri = 0; ri < 4; ri++) {
                    const float mv = Mld[rloc + ri][jt * 16 + l15];
                    const float t = fmaf(acc[jt][ri], scale, (&c4.x)[ri] + mv);
                    const bool rv = !tail || (rowb + ri < 125);
                    const bool cv = (jt < 7) | (l15 < 13);
                    acc[jt][ri] = (rv & cv) ? t : -1e30f;
                }
            }

            #pragma unroll
            for (int ri = 0; ri < 4; ri++) {
                float mx = acc[0][ri];
                #pragma unroll
                for (int jt = 1; jt < 8; jt++) mx = fmaxf(mx, acc[jt][ri]);
                mx = fmaxf(mx, __shfl_xor(mx, 1));
                mx = fmaxf(mx, __shfl_xor(mx, 2));
                mx = fmaxf(mx, __shfl_xor(mx, 4));
                mx = fmaxf(mx, __shfl_xor(mx, 8));
                float sum = 0.f;
                #pragma unroll
                for (int jt = 0; jt < 8; jt++) {
                    const float pv = __expf(acc[jt][ri] - mx);
                    acc[jt][ri] = pv; sum += pv;
                }
                sum += __shfl_xor(sum, 1);
                sum += __shfl_xor(sum, 2);
                sum += __shfl_xor(sum, 4);
                sum += __shfl_xor(sum, 8);
                rinv[mt][ri] = 1.0f / sum;
            }

            #pragma unroll
            for (int jt = 0; jt < 8; jt++)
                #pragma unroll
                for (int ri = 0; ri < 4; ri++)
                    P[(rloc + ri) * 136 + jt * 16 + l15] = f2bf(acc[jt][ri]);
        }

        v8bf vf[2][4];
        #pragma unroll
        for (int n2 = 0; n2 < 2; n2++)
            #pragma unroll
            for (int kk = 0; kk < 4; kk++)
                vf[n2][kk] = *(const v8bf*)(vb + (n2 * 16 + l15) * 128 + kk * 32 + lg * 8);

        v4f o[2][2];
        #pragma unroll
        for (int mt = 0; mt < 2; mt++)
            #pragma unroll
            for (int n2 = 0; n2 < 2; n2++) o[mt][n2] = z4;
        #pragma unroll
        for (int mt = 0; mt < 2; mt++) {
            v8bf pa[4];
            #pragma unroll
            for (int kk = 0; kk < 4; kk++)
                pa[kk] = *(const v8bf*)&P[(mt * 16 + l15) * 136 + kk * 32 + lg * 8];
            #pragma unroll
            for (int n2 = 0; n2 < 2; n2++)
                #pragma unroll
                for (int kk = 0; kk < 4; kk++)
                    o[mt][n2] = MFMA(pa[kk], vf[n2][kk], o[mt][n2]);
        }

        __syncthreads();
        #pragma unroll
        for (int mt = 0; mt < 2; mt++)
            #pragma unroll
            for (int n2 = 0; n2 < 2; n2++)
                #pragma unroll
                for (int ri = 0; ri < 4; ri++)
                    Olds[(mt * 16 + lg * 4 + ri) * 136 + hv * 32 + n2 * 16 + l15] =
                        f2bf(o[mt][n2][ri] * rinv[mt][ri]);
        __syncthreads();

        v8bf wf[2][4];
        #pragma unroll
        for (int n2 = 0; n2 < 2; n2++)
            #pragma unroll
            for (int kk = 0; kk < 4; kk++)
                wf[n2][kk] = *(const v8bf*)(Wp + (size_t)(hv * 32 + n2 * 16 + l15) * 128
                                            + kk * 32 + lg * 8);
        v4f po[2][2];
        #pragma unroll
        for (int mt = 0; mt < 2; mt++)
            #pragma unroll
            for (int n2 = 0; n2 < 2; n2++) po[mt][n2] = z4;
        #pragma unroll
        for (int mt = 0; mt < 2; mt++) {
            v8bf af[4];
            #pragma unroll
            for (int kk = 0; kk < 4; kk++)
                af[kk] = *(const v8bf*)&Olds[(mt * 16 + l15) * 136 + kk * 32 + lg * 8];
            #pragma unroll
            for (int n2 = 0; n2 < 2; n2++)
                #pragma unroll
                for (int kk = 0; kk < 4; kk++)
                    po[mt][n2] = MFMA(af[kk], wf[n2][kk], po[mt][n2]);
        }

        #pragma unroll
        for (int mt = 0; mt < 2; mt++)
            #pragma unroll
            for (int n2 = 0; n2 < 2; n2++)
                #pragma unroll
                for (int ri = 0; ri < 4; ri++) {
                    const int row = ch * 32 + mt * 16 + lg * 4 + ri;
                    if (row < 125)
                        out[((size_t)s * 256000 + (size_t)b * 125 + row) * 128
                            + hv * 32 + n2 * 16 + l15] = po[mt][n2][ri] + bpv[n2];
                }
        __syncthreads();
    }
}

// =================== SLOW PATH (round-3 validated fallback) ===================

__global__ __launch_bounds__(64) void fused_attn(
    const void* __restrict__ x, const void* __restrict__ y,
    const void* __restrict__ maskx, const void* __restrict__ masky,
    const void* __restrict__ wqkvx, const void* __restrict__ bqkvx,
    const void* __restrict__ wqkvy, const void* __restrict__ bqkvy,
    const void* __restrict__ rpb, const int* __restrict__ flag,
    float* __restrict__ out)
{
    const bool f32 = (*flag != 0);
    const int b = blockIdx.x >> 1;
    const int s = blockIdx.x & 1;
    const int h = blockIdx.y;
    const int lane = threadIdx.x;
    const int l15 = lane & 15, lg = lane >> 4;

    __shared__ u16 QL[125][40];
    __shared__ u16 KL[125][40];
    __shared__ u16 VT[32][136];
    __shared__ u16 P[32][136];

    const void* inS = s ? y : x;
    const void* inO = s ? x : y;
    const void* wS  = s ? wqkvy : wqkvx;
    const void* wO  = s ? wqkvx : wqkvy;
    const void* bS  = s ? bqkvy : bqkvx;
    const void* bO  = s ? bqkvx : bqkvy;
    const void* msk = s ? masky : maskx;

    const size_t inb = (size_t)b * (125 * 128);

    #pragma unroll
    for (int t = 0; t < 3; t++) {
        const void* src = t ? inO : inS;
        const void* wp  = t ? wO  : wS;
        const void* bp  = t ? bO  : bS;
        const int wrow = t * 128 + h * 32;

        v8bf bfr[2][4];
        float bv[2];
        #pragma unroll
        for (int nt = 0; nt < 2; nt++) {
            bv[nt] = load1(bp, wrow + nt * 16 + l15, f32);
            #pragma unroll
            for (int kk = 0; kk < 4; kk++)
                bfr[nt][kk] = load8(wp, (size_t)(wrow + nt * 16 + l15) * 128 + kk * 32 + lg * 8, f32);
        }
        #pragma unroll
        for (int mt = 0; mt < 8; mt++) {
            int ar = mt * 16 + l15; if (ar > 124) ar = 124;
            v8bf af[4];
            #pragma unroll
            for (int kk = 0; kk < 4; kk++)
                af[kk] = load8(src, inb + (size_t)ar * 128 + kk * 32 + lg * 8, f32);
            v4f a0 = {0.f,0.f,0.f,0.f}, a1 = {0.f,0.f,0.f,0.f};
            #pragma unroll
            for (int kk = 0; kk < 4; kk++) {
                a0 = MFMA(af[kk], bfr[0][kk], a0);
                a1 = MFMA(af[kk], bfr[1][kk], a1);
            }
            #pragma unroll
            for (int nt = 0; nt < 2; nt++) {
                const v4f acc = nt ? a1 : a0;
                const int col = nt * 16 + l15;
                #pragma unroll
                for (int ri = 0; ri < 4; ri++) {
                    const int wr = mt * 16 + lg * 4 + ri;
                    if (wr < 125) {
                        const u16 val = f2bf(acc[ri] + bv[nt]);
                        if (t == 0)      QL[wr][col] = val;
                        else if (t == 1) KL[wr][col] = val;
                        else             VT[col][wr] = val;
                    }
                }
            }
        }
    }
    for (int z = lane; z < 96; z += 64) VT[z & 31][125 + (z >> 5)] = 0;
    __syncthreads();

    v8bf kf[8];
    #pragma unroll
    for (int jt = 0; jt < 8; jt++) {
        int r = jt * 16 + l15; if (r > 124) r = 124;
        kf[jt] = *(const v8bf*)&KL[r][lg * 8];
    }
    v8bf vf[2][4];
    #pragma unroll
    for (int n2 = 0; n2 < 2; n2++)
        #pragma unroll
        for (int kk = 0; kk < 4; kk++)
            vf[n2][kk] = *(const v8bf*)&VT[n2 * 16 + l15][kk * 32 + lg * 8];

    int cb[8];
    #pragma unroll
    for (int jt = 0; jt < 8; jt++) {
        int col = jt * 16 + l15; if (col > 124) col = 124;
        const int q0 = col / 25, rem = col - q0 * 25, q1 = rem / 5, q2 = rem - q1 * 5;
        cb[jt] = 364 - (q0 * 81 + q1 * 9 + q2);
    }
    const size_t mbase = (size_t)(b & 255) * 15625;
    const float scale = 0.17677669529663689f;
    const v4f z4 = {0.f,0.f,0.f,0.f};

    for (int ch = 0; ch < 4; ch++) {
        v8bf qf[2];
        #pragma unroll
        for (int mt = 0; mt < 2; mt++) {
            int r = ch * 32 + mt * 16 + l15; if (r > 124) r = 124;
            qf[mt] = *(const v8bf*)&QL[r][lg * 8];
        }
        v4f acc[2][8];
        #pragma unroll
        for (int mt = 0; mt < 2; mt++)
            #pragma unroll
            for (int jt = 0; jt < 8; jt++) acc[mt][jt] = z4;
        #pragma unroll
        for (int jt = 0; jt < 8; jt++)
            #pragma unroll
            for (int mt = 0; mt < 2; mt++)
                acc[mt][jt] = MFMA(qf[mt], kf[jt], acc[mt][jt]);

        float rinv[2][4];
        #pragma unroll
        for (int mt = 0; mt < 2; mt++) {
            #pragma unroll
            for (int ri = 0; ri < 4; ri++) {
                const int row = ch * 32 + mt * 16 + lg * 4 + ri;
                const bool rv = row < 125;
                int prow = 0; size_t moff = 0;
                if (rv) {
                    const int p0 = row / 25, rem = row - p0 * 25, p1 = rem / 5, p2 = rem - p1 * 5;
                    prow = p0 * 81 + p1 * 9 + p2;
                    moff = mbase + (size_t)row * 125;
                }
                #pragma unroll
                for (int jt = 0; jt < 8; jt++) {
                    const int col = jt * 16 + l15;
                    float vv = -1e30f;
                    if (rv && col < 125)
                        vv = acc[mt][jt][ri] * scale
                           + load1(rpb, (size_t)(prow + cb[jt]) * 4 + h, f32)
                           + load1(msk, moff + col, f32);
                    acc[mt][jt][ri] = vv;
                }
                float mx = acc[mt][0][ri];
                #pragma unroll
                for (int jt = 1; jt < 8; jt++) mx = fmaxf(mx, acc[mt][jt][ri]);
                mx = fmaxf(mx, __shfl_xor(mx, 1));
                mx = fmaxf(mx, __shfl_xor(mx, 2));
                mx = fmaxf(mx, __shfl_xor(mx, 4));
                mx = fmaxf(mx, __shfl_xor(mx, 8));
                float sum = 0.f;
                #pragma unroll
                for (int jt = 0; jt < 8; jt++) {
                    const float pv = __expf(acc[mt][jt][ri] - mx);
                    acc[mt][jt][ri] = pv; sum += pv;
                }
                sum += __shfl_xor(sum, 1);
                sum += __shfl_xor(sum, 2);
                sum += __shfl_xor(sum, 4);
                sum += __shfl_xor(sum, 8);
                rinv[mt][ri] = 1.0f / sum;
            }
        }

        __syncthreads();
        #pragma unroll
        for (int mt = 0; mt < 2; mt++)
            #pragma unroll
            for (int jt = 0; jt < 8; jt++)
                #pragma unroll
                for (int ri = 0; ri < 4; ri++)
                    P[mt * 16 + lg * 4 + ri][jt * 16 + l15] = f2bf(acc[mt][jt][ri]);
        __syncthreads();

        v4f o[2][2];
        #pragma unroll
        for (int mt = 0; mt < 2; mt++)
            #pragma unroll
            for (int n2 = 0; n2 < 2; n2++) o[mt][n2] = z4;
        #pragma unroll
        for (int mt = 0; mt < 2; mt++) {
            v8bf pa[4];
            #pragma unroll
            for (int kk = 0; kk < 4; kk++)
                pa[kk] = *(const v8bf*)&P[mt * 16 + l15][kk * 32 + lg * 8];
            #pragma unroll
            for (int n2 = 0; n2 < 2; n2++)
                #pragma unroll
                for (int kk = 0; kk < 4; kk++)
                    o[mt][n2] = MFMA(pa[kk], vf[n2][kk], o[mt][n2]);
        }

        #pragma unroll
        for (int mt = 0; mt < 2; mt++)
            #pragma unroll
            for (int n2 = 0; n2 < 2; n2++)
                #pragma unroll
                for (int ri = 0; ri < 4; ri++) {
                    const int row = ch * 32 + mt * 16 + lg * 4 + ri;
                    if (row < 125)
                        out[((size_t)s * 256000 + (size_t)b * 125 + row) * 128
                            + h * 32 + n2 * 16 + l15] = o[mt][n2][ri] * rinv[mt][ri];
                }
    }
}

// ---- output projection, in place on fp32 d_out (fallback path only) ----
__global__ __launch_bounds__(256) void proj_kernel(
    const void* __restrict__ wpx, const void* __restrict__ bpx,
    const void* __restrict__ wpy, const void* __restrict__ bpy,
    const int* __restrict__ flag, float* io)
{
    const bool f32 = (*flag != 0);
    const int s  = blockIdx.y;
    const int bm = blockIdx.x;
    const void* W    = s ? wpy : wpx;
    const void* bias = s ? bpy : bpx;
    float* A = io + (size_t)s * 32768000;
    const int tid = threadIdx.x, lane = tid & 63, wv = tid >> 6;
    const int l15 = lane & 15, lg = lane >> 4;

    __shared__ u16 Wl[128][136];
    for (int i = tid * 8; i < 16384; i += 2048)
        *(v8bf*)&Wl[i >> 7][i & 127] = load8(W, i, f32);
    __syncthreads();

    const int mbase = bm * 64 + wv * 16;
    v4f acc[8];
    const v4f z4 = {0.f,0.f,0.f,0.f};
    #pragma unroll
    for (int nt = 0; nt < 8; nt++) acc[nt] = z4;

    const float* Ar = A + (size_t)(mbase + l15) * 128;
    v8bf afr[4];
    #pragma unroll
    for (int kk = 0; kk < 4; kk++) {
        union { u16 sI[8]; v8bf v; } U;
        float4 fa = *(const float4*)(Ar + kk * 32 + lg * 8);
        float4 fb = *(const float4*)(Ar + kk * 32 + lg * 8 + 4);
        U.sI[0] = f2bf(fa.x); U.sI[1] = f2bf(fa.y); U.sI[2] = f2bf(fa.z); U.sI[3] = f2bf(fa.w);
        U.sI[4] = f2bf(fb.x); U.sI[5] = f2bf(fb.y); U.sI[6] = f2bf(fb.z); U.sI[7] = f2bf(fb.w);
        afr[kk] = U.v;
    }
    #pragma unroll
    for (int kk = 0; kk < 4; kk++)
        #pragma unroll
        for (int nt = 0; nt < 8; nt++)
            acc[nt] = MFMA(afr[kk], *(const v8bf*)&Wl[nt * 16 + l15][kk * 32 + lg * 8], acc[nt]);

    #pragma unroll
    for (int nt = 0; nt < 8; nt++) {
        const int c = nt * 16 + l15;
        const float bv = load1(bias, c, f32);
        #pragma unroll
        for (int ri = 0; ri < 4; ri++)
            A[(size_t)(mbase + lg * 4 + ri) * 128 + c] = acc[nt][ri] + bv;
    }
}

extern "C" void kernel_launch(void* const* d_in, const int* in_sizes, int n_in,
                              void* d_out, int out_size, void* d_ws, size_t ws_size,
                              hipStream_t stream) {
    const float* x     = (const float*)d_in[0];
    const float* y     = (const float*)d_in[1];
    const float* maskx = (const float*)d_in[2];
    const float* masky = (const float*)d_in[3];
    const float* wqx   = (const float*)d_in[4];
    const float* bqx   = (const float*)d_in[5];
    const float* wqy   = (const float*)d_in[6];
    const float* bqy   = (const float*)d_in[7];
    const float* wpx   = (const float*)d_in[8];
    const float* bpx   = (const float*)d_in[9];
    const float* wpy   = (const float*)d_in[10];
    const float* bpy   = (const float*)d_in[11];
    const float* rpb   = (const float*)d_in[12];

    const size_t OFF_R0   = 0;
    const size_t OFF_Q    = 256000;
    const size_t OFF_K    = OFF_Q + 131072000;
    const size_t OFF_VT   = OFF_K + 131072000;
    const size_t OFF_WP   = OFF_VT + 134217728;
    const size_t OFF_BP   = OFF_WP + 65536;
    const size_t OFF_FLAG = OFF_BP + 512;
    const size_t NEED_MID = OFF_FLAG + 4;
    const size_t OFF_MT   = (NEED_MID + 15) & ~(size_t)15;
    const size_t NEED_BIG = OFF_MT + 32768000;                // 429,451,792
    const size_t OFF_RP   = NEED_BIG;
    const size_t NEED_BIG2 = OFF_RP + 256000;                 // 429,707,792
    const size_t OFF_CMB  = (NEED_BIG2 + 15) & ~(size_t)15;
    const size_t NEED_CMB = OFF_CMB + 131072000;              // ~560.8 MB (proven r18)

    if (ws_size >= NEED_MID) {
        u16*   wb   = (u16*)((char*)d_ws + OFF_R0);
        u16*   bb   = wb + 98304;
        float* rpbR = (float*)((char*)d_ws + OFF_R0);   // region0 phase 2 (tiers B/C)
        u16*   q    = (u16*)((char*)d_ws + OFF_Q);
        u16*   k    = (u16*)((char*)d_ws + OFF_K);
        u16*   vT   = (u16*)((char*)d_ws + OFF_VT);
        u16*   wpb  = (u16*)((char*)d_ws + OFF_WP);
        u16*   bpb  = (u16*)((char*)d_ws + OFF_BP);

        wconv_kernel<<<dim3(256, 2), 256, 0, stream>>>(wqx, bqx, wqy, bqy,
                                                       wpx, bpx, wpy, bpy,
                                                       wb, bb, wpb, bpb);
        if (ws_size >= NEED_CMB) {
            // tier D (r18 proven, 554 us): sequential roles, gather cmb build
            float* cmbT = (float*)((char*)d_ws + OFF_CMB);
            qkvc_kernel<<<dim3(2048, 2), 256, 0, stream>>>(x, y, wb, bb,
                                                           maskx, masky, rpb,
                                                           q, k, vT, cmbT);
            attn_cmb<<<4096, 256, 0, stream>>>(q, k, vT, cmbT,
                                               wpb, bpb, (float*)d_out);
        } else if (ws_size >= NEED_BIG2) {
            // tier A: r17 proven path
            float* mskP = (float*)((char*)d_ws + OFF_MT);
            float* rpbP = (float*)((char*)d_ws + OFF_RP);
            qkvt_kernel<<<dim3(1282, 2), 256, 0, stream>>>(x, y, wb, bb,
                                                           maskx, masky, rpb,
                                                           q, k, vT, mskP, rpbP);
            attn_swp<<<4096, 256, 0, stream>>>(q, k, vT, mskP, rpbP,
                                               wpb, bpb, (float*)d_out);
        } else if (ws_size >= NEED_BIG) {
            // tier B: split launches
            float* mskP = (float*)((char*)d_ws + OFF_MT);
            qkv_kernel<<<dim3(1024, 2), 256, 0, stream>>>(x, y, wb, bb, q, k, vT);
            rpbp_kernel<<<4, 256, 0, stream>>>(rpb, rpbR);       // overwrites wb/bb
            mskp_kernel<<<dim3(256, 2), 256, 0, stream>>>(maskx, masky, mskP);
            attn_swp<<<4096, 256, 0, stream>>>(q, k, vT, mskP, rpbR,
                                               wpb, bpb, (float*)d_out);
        } else {
            // tier C: mid (mask staged in LDS)
            qkv_kernel<<<dim3(1024, 2), 256, 0, stream>>>(x, y, wb, bb, q, k, vT);
            rpbt_kernel<<<4, 256, 0, stream>>>(rpb, rpbR);       // col-major
            attn_mld_kernel<<<4096, 256, 0, stream>>>(q, k, vT, maskx, masky, rpbR,
                                                      wpb, bpb, (float*)d_out);
        }
    } else {
        int* flag = (int*)d_ws;
        probe_kernel<<<1, 64, 0, stream>>>((const unsigned*)x, flag);
        fused_attn<<<dim3(4096, 4), 64, 0, stream>>>(x, y, maskx, masky,
                                                     wqx, bqx, wqy, bqy,
                                                     rpb, flag, (float*)d_out);
        proj_kernel<<<dim3(4000, 2), 256, 0, stream>>>(wpx, bpx, wpy, bpy,
                                                       flag, (float*)d_out);
    }
}

// Round 22
// 553.843 us; speedup vs baseline: 1.1686x; 1.0012x over previous
//
#include <hip/hip_runtime.h>
#include <stdint.h>

typedef unsigned short u16;                                   // raw bf16 bits
typedef __bf16 v8bf __attribute__((ext_vector_type(8)));      // MFMA A/B frag
typedef float  v4f  __attribute__((ext_vector_type(4)));      // MFMA C/D frag
typedef u16    u16x4 __attribute__((ext_vector_type(4)));

#define MFMA(a,b,c) __builtin_amdgcn_mfma_f32_16x16x32_bf16((a),(b),(c),0,0,0)
#define LOG2E 1.4426950408889634f

static __device__ __forceinline__ float bf2f(u16 u) {
    union { unsigned i; float f; } v; v.i = ((unsigned)u) << 16; return v.f;
}
static __device__ __forceinline__ u16 f2bf(float f) {         // RNE (manual)
    union { float f; unsigned i; } v; v.f = f;
    unsigned u = v.i;
    return (u16)((u + 0x7FFFu + ((u >> 16) & 1u)) >> 16);
}
static __device__ __forceinline__ u16 bfc(float f) {          // RNE via HW cvt
    union { __bf16 h; u16 u; } c; c.h = (__bf16)f; return c.u;
}
// fp32 -> bf16 frag (8 elems)
static __device__ __forceinline__ v8bf load8f(const float* p) {
    union { u16 s[8]; v8bf v; } U;
    float4 a = *(const float4*)p;
    float4 b = *(const float4*)(p + 4);
    U.s[0] = bfc(a.x); U.s[1] = bfc(a.y); U.s[2] = bfc(a.z); U.s[3] = bfc(a.w);
    U.s[4] = bfc(b.x); U.s[5] = bfc(b.y); U.s[6] = bfc(b.z); U.s[7] = bfc(b.w);
    return U.v;
}
// dual-dtype helpers (slow path only)
static __device__ __forceinline__ v8bf load8(const void* base, size_t off, bool f32) {
    union { u16 s[8]; v8bf v; } U;
    if (f32) return load8f((const float*)base + off);
    U.v = *(const v8bf*)((const u16*)base + off);
    return U.v;
}
static __device__ __forceinline__ float load1(const void* base, size_t off, bool f32) {
    return f32 ? ((const float*)base)[off] : bf2f(((const u16*)base)[off]);
}

// ---- dtype probe (slow path only) ----
__global__ void probe_kernel(const unsigned* __restrict__ x, int* __restrict__ flag) {
    if (threadIdx.x == 0 && blockIdx.x == 0) {
        int b16like = 0;
        for (int i = 0; i < 128; i++) {
            unsigned lo = x[i] & 0xFFFFu;
            int e = (lo >> 7) & 0xFF;
            if (e >= 110 && e <= 140) b16like++;
        }
        *flag = (b16like >= 64) ? 0 : 1;   // 1 => fp32 inputs
    }
}

// =================== FAST PATH (fp32 inputs, uses workspace) ===================

// ---- K0: convert qkv + proj weights/biases to bf16. grid (256, 2) ----
__global__ __launch_bounds__(256) void wconv_kernel(
    const float* __restrict__ wqkvx, const float* __restrict__ bqkvx,
    const float* __restrict__ wqkvy, const float* __restrict__ bqkvy,
    const float* __restrict__ wpx, const float* __restrict__ bpx,
    const float* __restrict__ wpy, const float* __restrict__ bpy,
    u16* __restrict__ wb, u16* __restrict__ bb,
    u16* __restrict__ wpb, u16* __restrict__ bpb)
{
    const int s = blockIdx.y;
    const int i = blockIdx.x * 256 + threadIdx.x;      // [0, 65536)
    if (i < 49152) {
        wb[(size_t)s * 49152 + i] = bfc((s ? wqkvy : wqkvx)[i]);
    } else {
        wpb[(size_t)s * 16384 + (i - 49152)] = bfc((s ? wpy : wpx)[i - 49152]);
    }
    if (i < 384)       bb[s * 384 + i]          = bfc((s ? bqkvy : bqkvx)[i]);
    else if (i < 512)  bpb[s * 128 + (i - 384)] = bfc((s ? bpy : bpx)[i - 384]);
}

// ---- device bodies shared by mega + standalone kernels ----
static __device__ __forceinline__ void mask_body(
    int w, int s, const float* maskx, const float* masky, float* mskP, int tid)
{
    const float* m = s ? masky : maskx;
    const size_t base = (size_t)w * 15625;
    float* dst = mskP + ((size_t)s * 256 + w) * 16000;
    for (int i = tid; i < 16000; i += 256) {
        const int row = i >> 7;
        int col = i & 127; if (col > 124) col = 124;
        dst[i] = m[base + (size_t)row * 125 + col] * LOG2E;
    }
}
static __device__ __forceinline__ void rpb_body(
    int h, const float* rpb, float* rpbP, int tid)
{
    for (int i = tid; i < 16000; i += 256) {
        const int row = i >> 7;                   // query (< 125)
        int col = i & 127; if (col > 124) col = 124;
        const int p0 = row / 25, prem = row - p0 * 25, p1 = prem / 5, p2 = prem - p1 * 5;
        const int q0 = col / 25, qrem = col - q0 * 25, q1 = qrem / 5, q2 = qrem - q1 * 5;
        const int idx = (p0 - q0 + 4) * 81 + (p1 - q1 + 4) * 9 + (p2 - q2 + 4);
        rpbP[(size_t)h * 16000 + i] = rpb[(size_t)idx * 4 + h] * LOG2E;
    }
}
// combined (mask + rpb) * LOG2E table (gather form; rpb is L1-resident 6KB)
static __device__ __forceinline__ void cmb_body(
    int w, int h, int s, const float* maskx, const float* masky,
    const float* rpb, float* cmb, int tid)
{
    const float* m = s ? masky : maskx;
    const size_t mbase = (size_t)w * 15625;
    float* dst = cmb + (((size_t)s * 256 + w) * 4 + h) * 16000;
    for (int i = tid; i < 16000; i += 256) {
        const int row = i >> 7;
        int col = i & 127; if (col > 124) col = 124;
        const int p0 = row / 25, prem = row - p0 * 25, p1 = prem / 5, p2 = prem - p1 * 5;
        const int q0 = col / 25, qrem = col - q0 * 25, q1 = qrem / 5, q2 = qrem - q1 * 5;
        const int idx = (p0 - q0 + 4) * 81 + (p1 - q1 + 4) * 9 + (p2 - q2 + 4);
        dst[i] = (m[mbase + (size_t)row * 125 + col] + rpb[(size_t)idx * 4 + h]) * LOG2E;
    }
}
// 256 tokens per block (64/wave, mt=0..3): weight fragments amortized 2x
static __device__ __forceinline__ void qkv_body(
    int mblk, int s, const float* x, const float* y,
    const u16* wb, const u16* bb,
    u16* q, u16* k, u16* vT, int tid)
{
    const float* A = s ? y : x;
    const u16* W  = wb + (size_t)s * 49152;
    const u16* Bb = bb + s * 384;
    const int lane = tid & 63, wv = tid >> 6;
    const int l15 = lane & 15, lg = lane >> 4;

    const int mbase = mblk * 256 + wv * 64;          // padded-m space [0, 262144)

    v8bf af[4][4];
    #pragma unroll
    for (int mt = 0; mt < 4; mt++) {
        const int mr = mbase + mt * 16 + l15;
        const int b  = mr >> 7;
        int n = mr & 127; if (n > 124) n = 124;      // clamp pad rows
        const float* arow = A + (size_t)(b * 125 + n) * 128;
        #pragma unroll
        for (int kk = 0; kk < 4; kk++)
            af[mt][kk] = load8f(arow + kk * 32 + lg * 8);
    }

    const v4f z4 = {0.f,0.f,0.f,0.f};
    #pragma unroll
    for (int nt = 0; nt < 24; nt++) {
        const int col0 = nt * 16;
        v8bf bfr[4];
        #pragma unroll
        for (int kk = 0; kk < 4; kk++)
            bfr[kk] = *(const v8bf*)(W + (size_t)(col0 + l15) * 128 + kk * 32 + lg * 8);

        const int three = col0 >> 7;                 // 0=q 1=k 2=v
        const int h     = (col0 >> 5) & 3;

        if (three < 2) {
            // q/k: SWAPPED MFMA -> D[channel][token]; packed u16x4 stores
            float bv[4];
            {
                const u16x4 bq = *(const u16x4*)&Bb[col0 + 4 * lg];
                #pragma unroll
                for (int r = 0; r < 4; r++) bv[r] = bf2f(bq[r]);
            }
            u16* dst = (three == 0) ? q : k;
            const int d0 = (col0 & 31) + 4 * lg;
            #pragma unroll
            for (int mt = 0; mt < 4; mt++) {
                v4f a0 = z4;
                #pragma unroll
                for (int kk = 0; kk < 4; kk++)
                    a0 = MFMA(bfr[kk], af[mt][kk], a0);
                const int t = mbase + mt * 16 + l15;
                const int b = t >> 7;
                int n = t & 127; if (n > 124) n = 124;   // dup-write same value
                const size_t hb = (size_t)(s * 2048 + b) * 4 + h;
                u16x4 pk;
                #pragma unroll
                for (int ri = 0; ri < 4; ri++) pk[ri] = bfc(a0[ri] + bv[ri]);
                *(u16x4*)&dst[hb * 4000 + n * 32 + d0] = pk;
            }
        } else {
            // v: unswapped -> vT packed store
            const float bv = bf2f(Bb[col0 + l15]);
            const int d = (col0 & 31) + l15;
            #pragma unroll
            for (int mt = 0; mt < 4; mt++) {
                v4f a0 = z4;
                #pragma unroll
                for (int kk = 0; kk < 4; kk++)
                    a0 = MFMA(af[mt][kk], bfr[kk], a0);
                const int m0 = mbase + mt * 16 + lg * 4;
                const int b  = m0 >> 7;
                const int n0 = m0 & 127;
                const size_t hb = (size_t)(s * 2048 + b) * 4 + h;
                u16x4 pk;
                #pragma unroll
                for (int ri = 0; ri < 4; ri++) pk[ri] = bfc(a0[ri] + bv);
                *(u16x4*)&vT[hb * 4096 + (size_t)d * 128 + n0] = pk;
            }
        }
    }
}

// ---- K2c (tier D): fused qkv + combined-table builder. grid (2048, 2).
// SEQUENTIAL roles (r18 proven): bx<1024 table slices, then qkv tiles. ----
__global__ __launch_bounds__(256) void qkvc_kernel(
    const float* __restrict__ x, const float* __restrict__ y,
    const u16* __restrict__ wb, const u16* __restrict__ bb,
    const float* __restrict__ maskx, const float* __restrict__ masky,
    const float* __restrict__ rpb,
    u16* __restrict__ q, u16* __restrict__ k, u16* __restrict__ vT,
    float* __restrict__ cmb)
{
    const int bx = blockIdx.x, by = blockIdx.y, tid = threadIdx.x;
    if (bx < 1024) cmb_body(bx >> 2, bx & 3, by, maskx, masky, rpb, cmb, tid);
    else           qkv_body(bx - 1024, by, x, y, wb, bb, q, k, vT, tid);
}

// ---- K2a (tier A): fused qkv + split table builders. grid (1282, 2) ----
__global__ __launch_bounds__(256) void qkvt_kernel(
    const float* __restrict__ x, const float* __restrict__ y,
    const u16* __restrict__ wb, const u16* __restrict__ bb,
    const float* __restrict__ maskx, const float* __restrict__ masky,
    const float* __restrict__ rpb,
    u16* __restrict__ q, u16* __restrict__ k, u16* __restrict__ vT,
    float* __restrict__ mskP, float* __restrict__ rpbP)
{
    const int bx = blockIdx.x, by = blockIdx.y, tid = threadIdx.x;
    if (bx < 256)       mask_body(bx, by, maskx, masky, mskP, tid);
    else if (bx < 258)  rpb_body((bx - 256) * 2 + by, rpb, rpbP, tid);
    else                qkv_body(bx - 258, by, x, y, wb, bb, q, k, vT, tid);
}

// ---- K2b (tier B/C): standalone qkv. grid (1024, 2) ----
__global__ __launch_bounds__(256) void qkv_kernel(
    const float* __restrict__ x, const float* __restrict__ y,
    const u16* __restrict__ wb, const u16* __restrict__ bb,
    u16* __restrict__ q, u16* __restrict__ k, u16* __restrict__ vT)
{
    qkv_body(blockIdx.x, blockIdx.y, x, y, wb, bb, q, k, vT, threadIdx.x);
}

// ---- standalone table kernels ----
__global__ __launch_bounds__(256) void mskp_kernel(
    const float* __restrict__ maskx, const float* __restrict__ masky,
    float* __restrict__ mskP)
{
    mask_body(blockIdx.x, blockIdx.y, maskx, masky, mskP, threadIdx.x);
}
__global__ __launch_bounds__(256) void rpbp_kernel(
    const float* __restrict__ rpb, float* __restrict__ rpbP)
{
    rpb_body(blockIdx.x, rpb, rpbP, threadIdx.x);
}

// ---- K1 (mid tier): rpbT[h][col(key)][row(query) pad128] fp32 (col-major) ----
__global__ __launch_bounds__(256) void rpbt_kernel(
    const float* __restrict__ rpb, float* __restrict__ rpbT)
{
    const int h = blockIdx.x;
    for (int i = threadIdx.x; i < 16000; i += 256) {
        const int col = i >> 7, row = i & 127;
        float v = 0.f;
        if (row < 125) {
            const int p0 = row / 25, prem = row - p0 * 25, p1 = prem / 5, p2 = prem - p1 * 5;
            const int q0 = col / 25, qrem = col - q0 * 25, q1 = qrem / 5, q2 = qrem - q1 * 5;
            const int idx = (p0 - q0 + 4) * 81 + (p1 - q1 + 4) * 9 + (p2 - q2 + 4);
            v = rpb[(size_t)idx * 4 + h];
        }
        rpbT[(size_t)h * 16000 + i] = v;
    }
}

// ---- K3 (tier D): attn with COMBINED table (frozen r18 form, ~240 us) ----
__global__ __launch_bounds__(256) void attn_cmb(
    const u16* __restrict__ q, const u16* __restrict__ k, const u16* __restrict__ vT,
    const float* __restrict__ cmb,
    const u16* __restrict__ wpb, const u16* __restrict__ bpb,
    float* __restrict__ out)
{
    const int bid = blockIdx.x;                    // 4096 = 8 xcd * 512
    const int rep = (bid >> 3) & 15;               // same-w blocks -> same XCD
    const int w   = ((bid >> 7) << 3) | (bid & 7);
    const int s = rep & 1, b = (rep >> 1) * 256 + w;
    const int tid = threadIdx.x;
    const int hv = tid >> 6;                       // wave = head
    const int lane = tid & 63, l15 = lane & 15, lg = lane >> 4;

    __shared__ u16 Pl[4][16][140];                 // per-wave P^T slab (17920 B)
    __shared__ u16 Olds[32][136];                  // shared O tile (8704 B)
    u16* P = &Pl[hv][0][0];

    const u16* qb = q  + ((size_t)(s * 2048 + b) * 4 + hv) * 4000;
    const u16* kb = k  + ((size_t)((1 - s) * 2048 + b) * 4 + hv) * 4000;
    const u16* vb = vT + ((size_t)((1 - s) * 2048 + b) * 4 + hv) * 4096;
    const float* tP = cmb + (((size_t)s * 256 + w) * 4 + hv) * 16000;
    const u16* Wp = wpb + (size_t)s * 16384;       // [c][d] bf16
    float bpv[2];
    #pragma unroll
    for (int n2 = 0; n2 < 2; n2++)
        bpv[n2] = bf2f(bpb[s * 128 + hv * 32 + n2 * 16 + l15]);

    v8bf kf[8];                                    // resident K frags (A-operand)
    #pragma unroll
    for (int jt = 0; jt < 8; jt++) {
        int c = jt * 16 + l15; if (c > 124) c = 124;
        kf[jt] = *(const v8bf*)(kb + c * 32 + lg * 8);
    }

    const float scale2 = 0.17677669529663689f * LOG2E;   // 32^-0.5 * log2(e)
    const v4f z4 = {0.f,0.f,0.f,0.f};

    for (int ch = 0; ch < 4; ch++) {
        v4f ot[2][2];                              // O^T accum [mt][n2]
        float rinv[2];

        #pragma unroll
        for (int mt = 0; mt < 2; mt++) {
            int qr = ch * 32 + mt * 16 + l15; if (qr > 124) qr = 124;
            const v8bf qf = *(const v8bf*)(qb + qr * 32 + lg * 8);

            v4f acc[8];
            #pragma unroll
            for (int jt = 0; jt < 8; jt++) acc[jt] = z4;
            #pragma unroll
            for (int jt = 0; jt < 8; jt++)
                acc[jt] = MFMA(kf[jt], qf, acc[jt]);   // SWAPPED: D[key][qrow]

            // combined bias+mask (log2-domain), ONE float4 per jt
            const float* trow = tP + (size_t)qr * 128 + 4 * lg;
            #pragma unroll
            for (int jt = 0; jt < 8; jt++) {
                const float4 tb4 = *(const float4*)(trow + jt * 16);
                #pragma unroll
                for (int ri = 0; ri < 4; ri++) {
                    float t = fmaf(acc[jt][ri], scale2, (&tb4.x)[ri]);
                    if (jt == 7) t = (4 * lg + ri < 13) ? t : -1e30f;  // key >= 125
                    acc[jt][ri] = t;
                }
            }

            // lane-local softmax (row = l15), 2-shfl reduce across lg groups
            float mx = acc[0][0];
            #pragma unroll
            for (int jt = 0; jt < 8; jt++)
                #pragma unroll
                for (int ri = 0; ri < 4; ri++) mx = fmaxf(mx, acc[jt][ri]);
            mx = fmaxf(mx, __shfl_xor(mx, 16));
            mx = fmaxf(mx, __shfl_xor(mx, 32));
            float sum = 0.f;
            #pragma unroll
            for (int jt = 0; jt < 8; jt++)
                #pragma unroll
                for (int ri = 0; ri < 4; ri++) {
                    const float pv = __builtin_amdgcn_exp2f(acc[jt][ri] - mx);
                    acc[jt][ri] = pv; sum += pv;
                }
            sum += __shfl_xor(sum, 16);
            sum += __shfl_xor(sum, 32);
            rinv[mt] = 1.0f / sum;                 // lane-scalar (qrow = l15)

            // pack P^T (bf16 pairs) into wave-local LDS: P[l15][key]
            #pragma unroll
            for (int jt = 0; jt < 8; jt++) {
                const int kb2 = jt * 16 + 4 * lg;
                const unsigned w0 = (unsigned)f2bf(acc[jt][0]) | ((unsigned)f2bf(acc[jt][1]) << 16);
                const unsigned w1 = (unsigned)f2bf(acc[jt][2]) | ((unsigned)f2bf(acc[jt][3]) << 16);
                *(unsigned*)&P[l15 * 140 + kb2]     = w0;
                *(unsigned*)&P[l15 * 140 + kb2 + 2] = w1;
            }

            // PV swapped: A = V^T frag (vT natural layout), B = P^T frag
            ot[mt][0] = z4; ot[mt][1] = z4;
            #pragma unroll
            for (int kk = 0; kk < 4; kk++) {
                const v8bf pb = *(const v8bf*)&P[l15 * 140 + kk * 32 + lg * 8];
                #pragma unroll
                for (int n2 = 0; n2 < 2; n2++) {
                    const v8bf va = *(const v8bf*)(vb + (n2 * 16 + l15) * 128 + kk * 32 + lg * 8);
                    ot[mt][n2] = MFMA(va, pb, ot[mt][n2]);
                }
            }
        }

        __syncthreads();                           // prior proj reads of Olds done
        // O^T -> Olds[chunk row][channel], rinv folded (lane-scalar), packed b32
        #pragma unroll
        for (int mt = 0; mt < 2; mt++)
            #pragma unroll
            for (int n2 = 0; n2 < 2; n2++) {
                const int row = mt * 16 + l15;
                const int col = hv * 32 + n2 * 16 + 4 * lg;
                const unsigned w0 = (unsigned)f2bf(ot[mt][n2][0] * rinv[mt])
                                  | ((unsigned)f2bf(ot[mt][n2][1] * rinv[mt]) << 16);
                const unsigned w1 = (unsigned)f2bf(ot[mt][n2][2] * rinv[mt])
                                  | ((unsigned)f2bf(ot[mt][n2][3] * rinv[mt]) << 16);
                *(unsigned*)&Olds[row][col]     = w0;
                *(unsigned*)&Olds[row][col + 2] = w1;
            }
        __syncthreads();                           // O tile complete

        // ---- fused projection: this wave's 32 output cols ----
        v8bf wf[2][4];
        #pragma unroll
        for (int n2 = 0; n2 < 2; n2++)
            #pragma unroll
            for (int kk = 0; kk < 4; kk++)
                wf[n2][kk] = *(const v8bf*)(Wp + (size_t)(hv * 32 + n2 * 16 + l15) * 128
                                            + kk * 32 + lg * 8);
        v4f po[2][2];
        #pragma unroll
        for (int mt = 0; mt < 2; mt++)
            #pragma unroll
            for (int n2 = 0; n2 < 2; n2++) po[mt][n2] = z4;
        #pragma unroll
        for (int mt = 0; mt < 2; mt++) {
            v8bf af[4];
            #pragma unroll
            for (int kk = 0; kk < 4; kk++)
                af[kk] = *(const v8bf*)&Olds[mt * 16 + l15][kk * 32 + lg * 8];
            #pragma unroll
            for (int n2 = 0; n2 < 2; n2++)
                #pragma unroll
                for (int kk = 0; kk < 4; kk++)
                    po[mt][n2] = MFMA(af[kk], wf[n2][kk], po[mt][n2]);
        }

        #pragma unroll
        for (int mt = 0; mt < 2; mt++)
            #pragma unroll
            for (int n2 = 0; n2 < 2; n2++)
                #pragma unroll
                for (int ri = 0; ri < 4; ri++) {
                    const int row = ch * 32 + mt * 16 + lg * 4 + ri;
                    if (row < 125)
                        out[((size_t)s * 256000 + (size_t)b * 125 + row) * 128
                            + hv * 32 + n2 * 16 + l15] = po[mt][n2][ri] + bpv[n2];
                }
        __syncthreads();                           // proj reads done before next chunk
    }
}

// ---- K3 (tiers A/B): EXACT r13/r15 frozen attn ----
__global__ __launch_bounds__(256) void attn_swp(
    const u16* __restrict__ q, const u16* __restrict__ k, const u16* __restrict__ vT,
    const float* __restrict__ mskP, const float* __restrict__ rpbP,
    const u16* __restrict__ wpb, const u16* __restrict__ bpb,
    float* __restrict__ out)
{
    const int bid = blockIdx.x;
    const int rep = (bid >> 3) & 15;
    const int w   = ((bid >> 7) << 3) | (bid & 7);
    const int s = rep & 1, b = (rep >> 1) * 256 + w;
    const int tid = threadIdx.x;
    const int hv = tid >> 6;
    const int lane = tid & 63, l15 = lane & 15, lg = lane >> 4;

    __shared__ u16 Pl[4][16][140];
    __shared__ u16 Olds[32][136];
    u16* P = &Pl[hv][0][0];

    const u16* qb = q  + ((size_t)(s * 2048 + b) * 4 + hv) * 4000;
    const u16* kb = k  + ((size_t)((1 - s) * 2048 + b) * 4 + hv) * 4000;
    const u16* vb = vT + ((size_t)((1 - s) * 2048 + b) * 4 + hv) * 4096;
    const float* mP = mskP + ((size_t)s * 256 + w) * 16000;
    const float* rP = rpbP + (size_t)hv * 16000;
    const u16* Wp = wpb + (size_t)s * 16384;
    float bpv[2];
    #pragma unroll
    for (int n2 = 0; n2 < 2; n2++)
        bpv[n2] = bf2f(bpb[s * 128 + hv * 32 + n2 * 16 + l15]);

    v8bf kf[8];
    #pragma unroll
    for (int jt = 0; jt < 8; jt++) {
        int c = jt * 16 + l15; if (c > 124) c = 124;
        kf[jt] = *(const v8bf*)(kb + c * 32 + lg * 8);
    }

    const float scale2 = 0.17677669529663689f * LOG2E;
    const v4f z4 = {0.f,0.f,0.f,0.f};

    for (int ch = 0; ch < 4; ch++) {
        v4f ot[2][2];
        float rinv[2];

        #pragma unroll
        for (int mt = 0; mt < 2; mt++) {
            int qr = ch * 32 + mt * 16 + l15; if (qr > 124) qr = 124;
            const v8bf qf = *(const v8bf*)(qb + qr * 32 + lg * 8);

            v4f acc[8];
            #pragma unroll
            for (int jt = 0; jt < 8; jt++) acc[jt] = z4;
            #pragma unroll
            for (int jt = 0; jt < 8; jt++)
                acc[jt] = MFMA(kf[jt], qf, acc[jt]);

            const float* rrow = rP + (size_t)qr * 128 + 4 * lg;
            const float* mrow = mP + (size_t)qr * 128 + 4 * lg;
            #pragma unroll
            for (int jt = 0; jt < 8; jt++) {
                const float4 rb4 = *(const float4*)(rrow + jt * 16);
                const float4 mv4 = *(const float4*)(mrow + jt * 16);
                #pragma unroll
                for (int ri = 0; ri < 4; ri++) {
                    float t = fmaf(acc[jt][ri], scale2, (&rb4.x)[ri] + (&mv4.x)[ri]);
                    if (jt == 7) t = (4 * lg + ri < 13) ? t : -1e30f;
                    acc[jt][ri] = t;
                }
            }

            float mx = acc[0][0];
            #pragma unroll
            for (int jt = 0; jt < 8; jt++)
                #pragma unroll
                for (int ri = 0; ri < 4; ri++) mx = fmaxf(mx, acc[jt][ri]);
            mx = fmaxf(mx, __shfl_xor(mx, 16));
            mx = fmaxf(mx, __shfl_xor(mx, 32));
            float sum = 0.f;
            #pragma unroll
            for (int jt = 0; jt < 8; jt++)
                #pragma unroll
                for (int ri = 0; ri < 4; ri++) {
                    const float pv = __builtin_amdgcn_exp2f(acc[jt][ri] - mx);
                    acc[jt][ri] = pv; sum += pv;
                }
            sum += __shfl_xor(sum, 16);
            sum += __shfl_xor(sum, 32);
            rinv[mt] = 1.0f / sum;

            #pragma unroll
            for (int jt = 0; jt < 8; jt++) {
                const int kb2 = jt * 16 + 4 * lg;
                const unsigned w0 = (unsigned)f2bf(acc[jt][0]) | ((unsigned)f2bf(acc[jt][1]) << 16);
                const unsigned w1 = (unsigned)f2bf(acc[jt][2]) | ((unsigned)f2bf(acc[jt][3]) << 16);
                *(unsigned*)&P[l15 * 140 + kb2]     = w0;
                *(unsigned*)&P[l15 * 140 + kb2 + 2] = w1;
            }

            ot[mt][0] = z4; ot[mt][1] = z4;
            #pragma unroll
            for (int kk = 0; kk < 4; kk++) {
                const v8bf pb = *(const v8bf*)&P[l15 * 140 + kk * 32 + lg * 8];
                #pragma unroll
                for (int n2 = 0; n2 < 2; n2++) {
                    const v8bf va = *(const v8bf*)(vb + (n2 * 16 + l15) * 128 + kk * 32 + lg * 8);
                    ot[mt][n2] = MFMA(va, pb, ot[mt][n2]);
                }
            }
        }

        __syncthreads();
        #pragma unroll
        for (int mt = 0; mt < 2; mt++)
            #pragma unroll
            for (int n2 = 0; n2 < 2; n2++) {
                const int row = mt * 16 + l15;
                const int col = hv * 32 + n2 * 16 + 4 * lg;
                const unsigned w0 = (unsigned)f2bf(ot[mt][n2][0] * rinv[mt])
                                  | ((unsigned)f2bf(ot[mt][n2][1] * rinv[mt]) << 16);
                const unsigned w1 = (unsigned)f2bf(ot[mt][n2][2] * rinv[mt])
                                  | ((unsigned)f2bf(ot[mt][n2][3] * rinv[mt]) << 16);
                *(unsigned*)&Olds[row][col]     = w0;
                *(unsigned*)&Olds[row][col + 2] = w1;
            }
        __syncthreads();

        v8bf wf[2][4];
        #pragma unroll
        for (int n2 = 0; n2 < 2; n2++)
            #pragma unroll
            for (int kk = 0; kk < 4; kk++)
                wf[n2][kk] = *(const v8bf*)(Wp + (size_t)(hv * 32 + n2 * 16 + l15) * 128
                                            + kk * 32 + lg * 8);
        v4f po[2][2];
        #pragma unroll
        for (int mt = 0; mt < 2; mt++)
            #pragma unroll
            for (int n2 = 0; n2 < 2; n2++) po[mt][n2] = z4;
        #pragma unroll
        for (int mt = 0; mt < 2; mt++) {
            v8bf af[4];
            #pragma unroll
            for (int kk = 0; kk < 4; kk++)
                af[kk] = *(const v8bf*)&Olds[mt * 16 + l15][kk * 32 + lg * 8];
            #pragma unroll
            for (int n2 = 0; n2 < 2; n2++)
                #pragma unroll
                for (int kk = 0; kk < 4; kk++)
                    po[mt][n2] = MFMA(af[kk], wf[n2][kk], po[mt][n2]);
        }

        #pragma unroll
        for (int mt = 0; mt < 2; mt++)
            #pragma unroll
            for (int n2 = 0; n2 < 2; n2++)
                #pragma unroll
                for (int ri = 0; ri < 4; ri++) {
                    const int row = ch * 32 + mt * 16 + lg * 4 + ri;
                    if (row < 125)
                        out[((size_t)s * 256000 + (size_t)b * 125 + row) * 128
                            + hv * 32 + n2 * 16 + l15] = po[mt][n2][ri] + bpv[n2];
                }
        __syncthreads();
    }
}

// ---- K3 (mid tier): round-8 validated kernel (mask staged in LDS), fp32 in ----
__global__ __launch_bounds__(256) void attn_mld_kernel(
    const u16* __restrict__ q, const u16* __restrict__ k, const u16* __restrict__ vT,
    const float* __restrict__ maskx, const float* __restrict__ masky,
    const float* __restrict__ rpbT,
    const u16* __restrict__ wpb, const u16* __restrict__ bpb,
    float* __restrict__ out)
{
    const int bid = blockIdx.x;
    const int rep = (bid >> 3) & 15;
    const int w   = ((bid >> 7) << 3) | (bid & 7);
    const int s = rep & 1, b = (rep >> 1) * 256 + w;
    const int tid = threadIdx.x;
    const int hv = tid >> 6;
    const int lane = tid & 63, l15 = lane & 15, lg = lane >> 4;

    __shared__ u16 Pb[4][32][136];
    __shared__ float Mld[32][132];
    u16* P    = &Pb[hv][0][0];
    u16* Olds = &Pb[0][0][0];

    const u16* qb = q  + ((size_t)(s * 2048 + b) * 4 + hv) * 4000;
    const u16* kb = k  + ((size_t)((1 - s) * 2048 + b) * 4 + hv) * 4000;
    const u16* vb = vT + ((size_t)((1 - s) * 2048 + b) * 4 + hv) * 4096;
    const float* msk = s ? masky : maskx;
    const size_t mbase = (size_t)w * 15625;
    const float* rT = rpbT + (size_t)hv * 16000;
    const u16* Wp = wpb + (size_t)s * 16384;
    float bpv[2];
    #pragma unroll
    for (int n2 = 0; n2 < 2; n2++)
        bpv[n2] = bf2f(bpb[s * 128 + hv * 32 + n2 * 16 + l15]);

    int colc[8];
    #pragma unroll
    for (int jt = 0; jt < 8; jt++) {
        int c = jt * 16 + l15; if (c > 124) c = 124;
        colc[jt] = c;
    }

    v8bf kf[8];
    #pragma unroll
    for (int jt = 0; jt < 8; jt++)
        kf[jt] = *(const v8bf*)(kb + colc[jt] * 32 + lg * 8);

    const float scale = 0.17677669529663689f;
    const v4f z4 = {0.f,0.f,0.f,0.f};

    for (int ch = 0; ch < 4; ch++) {
        for (int i = tid; i < 4096; i += 256) {
            const int r = i >> 7, c = i & 127;
            int rc = ch * 32 + r; if (rc > 124) rc = 124;
            int cc = c;          if (cc > 124) cc = 124;
            Mld[r][c] = msk[mbase + (size_t)rc * 125 + cc];
        }
        __syncthreads();

        float rinv[2][4];
        #pragma unroll
        for (int mt = 0; mt < 2; mt++) {
            int qr = ch * 32 + mt * 16 + l15; if (qr > 124) qr = 124;
            const v8bf qf = *(const v8bf*)(qb + qr * 32 + lg * 8);

            v4f acc[8];
            #pragma unroll
            for (int jt = 0; jt < 8; jt++) acc[jt] = z4;
            #pragma unroll
            for (int jt = 0; jt < 8; jt++)
                acc[jt] = MFMA(qf, kf[jt], acc[jt]);

            const int rloc = mt * 16 + lg * 4;
            const int rowb = ch * 32 + rloc;
            const bool tail = (ch == 3) && (mt == 1);

            #pragma unroll
            for (int jt = 0; jt < 8; jt++) {
                const float4 c4 = *(const float4*)(rT + colc[jt] * 128 + rowb);
                #pragma unroll
                for (int ri = 0; ri < 4; ri++) {
                    const float mv = Mld[rloc + ri][jt * 16 + l15];
                    const float t = fmaf(acc[jt][ri], scale, (&c4.x)[ri] + mv);
                    const bool rv = !tail || (rowb + ri < 125);
                    const bool cv = (jt < 7) | (l15 < 13);
                    acc[jt][ri] = (rv & cv) ? t : -1e30f;
                }
            }

            #pragma unroll
            for (int ri = 0; ri < 4; ri++) {
                float mx = acc[0][ri];
                #pragma unroll
                for (int jt = 1; jt < 8; jt++) mx = fmaxf(mx, acc[jt][ri]);
                mx = fmaxf(mx, __shfl_xor(mx, 1));
                mx = fmaxf(mx, __shfl_xor(mx, 2));
                mx = fmaxf(mx, __shfl_xor(mx, 4));
                mx = fmaxf(mx, __shfl_xor(mx, 8));
                float sum = 0.f;
                #pragma unroll
                for (int jt = 0; jt < 8; jt++) {
                    const float pv = __expf(acc[jt][ri] - mx);
                    acc[jt][ri] = pv; sum += pv;
                }
                sum += __shfl_xor(sum, 1);
                sum += __shfl_xor(sum, 2);
                sum += __shfl_xor(sum, 4);
                sum += __shfl_xor(sum, 8);
                rinv[mt][ri] = 1.0f / sum;
            }

            #pragma unroll
            for (int jt = 0; jt < 8; jt++)
                #pragma unroll
                for (int ri = 0; ri < 4; ri++)
                    P[(rloc + ri) * 136 + jt * 16 + l15] = f2bf(acc[jt][ri]);
        }

        v8bf vf[2][4];
        #pragma unroll
        for (int n2 = 0; n2 < 2; n2++)
            #pragma unroll
            for (int kk = 0; kk < 4; kk++)
                vf[n2][kk] = *(const v8bf*)(vb + (n2 * 16 + l15) * 128 + kk * 32 + lg * 8);

        v4f o[2][2];
        #pragma unroll
        for (int mt = 0; mt < 2; mt++)
            #pragma unroll
            for (int n2 = 0; n2 < 2; n2++) o[mt][n2] = z4;
        #pragma unroll
        for (int mt = 0; mt < 2; mt++) {
            v8bf pa[4];
            #pragma unroll
            for (int kk = 0; kk < 4; kk++)
                pa[kk] = *(const v8bf*)&P[(mt * 16 + l15) * 136 + kk * 32 + lg * 8];
            #pragma unroll
            for (int n2 = 0; n2 < 2; n2++)
                #pragma unroll
                for (int kk = 0; kk < 4; kk++)
                    o[mt][n2] = MFMA(pa[kk], vf[n2][kk], o[mt][n2]);
        }

        __syncthreads();
        #pragma unroll
        for (int mt = 0; mt < 2; mt++)
            #pragma unroll
            for (int n2 = 0; n2 < 2; n2++)
                #pragma unroll
                for (int ri = 0; ri < 4; ri++)
                    Olds[(mt * 16 + lg * 4 + ri) * 136 + hv * 32 + n2 * 16 + l15] =
                        f2bf(o[mt][n2][ri] * rinv[mt][ri]);
        __syncthreads();

        v8bf wf[2][4];
        #pragma unroll
        for (int n2 = 0; n2 < 2; n2++)
            #pragma unroll
            for (int kk = 0; kk < 4; kk++)
                wf[n2][kk] = *(const v8bf*)(Wp + (size_t)(hv * 32 + n2 * 16 + l15) * 128
                                            + kk * 32 + lg * 8);
        v4f po[2][2];
        #pragma unroll
        for (int mt = 0; mt < 2; mt++)
            #pragma unroll
            for (int n2 = 0; n2 < 2; n2++) po[mt][n2] = z4;
        #pragma unroll
        for (int mt = 0; mt < 2; mt++) {
            v8bf af[4];
            #pragma unroll
            for (int kk = 0; kk < 4; kk++)
                af[kk] = *(const v8bf*)&Olds[(mt * 16 + l15) * 136 + kk * 32 + lg * 8];
            #pragma unroll
            for (int n2 = 0; n2 < 2; n2++)
                #pragma unroll
                for (int kk = 0; kk < 4; kk++)
                    po[mt][n2] = MFMA(af[kk], wf[n2][kk], po[mt][n2]);
        }

        #pragma unroll
        for (int mt = 0; mt < 2; mt++)
            #pragma unroll
            for (int n2 = 0; n2 < 2; n2++)
                #pragma unroll
                for (int ri = 0; ri < 4; ri++) {
                    const int row = ch * 32 + mt * 16 + lg * 4 + ri;
                    if (row < 125)
                        out[((size_t)s * 256000 + (size_t)b * 125 + row) * 128
                            + hv * 32 + n2 * 16 + l15] = po[mt][n2][ri] + bpv[n2];
                }
        __syncthreads();
    }
}

// =================== SLOW PATH (round-3 validated fallback) ===================

__global__ __launch_bounds__(64) void fused_attn(
    const void* __restrict__ x, const void* __restrict__ y,
    const void* __restrict__ maskx, const void* __restrict__ masky,
    const void* __restrict__ wqkvx, const void* __restrict__ bqkvx,
    const void* __restrict__ wqkvy, const void* __restrict__ bqkvy,
    const void* __restrict__ rpb, const int* __restrict__ flag,
    float* __restrict__ out)
{
    const bool f32 = (*flag != 0);
    const int b = blockIdx.x >> 1;
    const int s = blockIdx.x & 1;
    const int h = blockIdx.y;
    const int lane = threadIdx.x;
    const int l15 = lane & 15, lg = lane >> 4;

    __shared__ u16 QL[125][40];
    __shared__ u16 KL[125][40];
    __shared__ u16 VT[32][136];
    __shared__ u16 P[32][136];

    const void* inS = s ? y : x;
    const void* inO = s ? x : y;
    const void* wS  = s ? wqkvy : wqkvx;
    const void* wO  = s ? wqkvx : wqkvy;
    const void* bS  = s ? bqkvy : bqkvx;
    const void* bO  = s ? bqkvx : bqkvy;
    const void* msk = s ? masky : maskx;

    const size_t inb = (size_t)b * (125 * 128);

    #pragma unroll
    for (int t = 0; t < 3; t++) {
        const void* src = t ? inO : inS;
        const void* wp  = t ? wO  : wS;
        const void* bp  = t ? bO  : bS;
        const int wrow = t * 128 + h * 32;

        v8bf bfr[2][4];
        float bv[2];
        #pragma unroll
        for (int nt = 0; nt < 2; nt++) {
            bv[nt] = load1(bp, wrow + nt * 16 + l15, f32);
            #pragma unroll
            for (int kk = 0; kk < 4; kk++)
                bfr[nt][kk] = load8(wp, (size_t)(wrow + nt * 16 + l15) * 128 + kk * 32 + lg * 8, f32);
        }
        #pragma unroll
        for (int mt = 0; mt < 8; mt++) {
            int ar = mt * 16 + l15; if (ar > 124) ar = 124;
            v8bf af[4];
            #pragma unroll
            for (int kk = 0; kk < 4; kk++)
                af[kk] = load8(src, inb + (size_t)ar * 128 + kk * 32 + lg * 8, f32);
            v4f a0 = {0.f,0.f,0.f,0.f}, a1 = {0.f,0.f,0.f,0.f};
            #pragma unroll
            for (int kk = 0; kk < 4; kk++) {
                a0 = MFMA(af[kk], bfr[0][kk], a0);
                a1 = MFMA(af[kk], bfr[1][kk], a1);
            }
            #pragma unroll
            for (int nt = 0; nt < 2; nt++) {
                const v4f acc = nt ? a1 : a0;
                const int col = nt * 16 + l15;
                #pragma unroll
                for (int ri = 0; ri < 4; ri++) {
                    const int wr = mt * 16 + lg * 4 + ri;
                    if (wr < 125) {
                        const u16 val = f2bf(acc[ri] + bv[nt]);
                        if (t == 0)      QL[wr][col] = val;
                        else if (t == 1) KL[wr][col] = val;
                        else             VT[col][wr] = val;
                    }
                }
            }
        }
    }
    for (int z = lane; z < 96; z += 64) VT[z & 31][125 + (z >> 5)] = 0;
    __syncthreads();

    v8bf kf[8];
    #pragma unroll
    for (int jt = 0; jt < 8; jt++) {
        int r = jt * 16 + l15; if (r > 124) r = 124;
        kf[jt] = *(const v8bf*)&KL[r][lg * 8];
    }
    v8bf vf[2][4];
    #pragma unroll
    for (int n2 = 0; n2 < 2; n2++)
        #pragma unroll
        for (int kk = 0; kk < 4; kk++)
            vf[n2][kk] = *(const v8bf*)&VT[n2 * 16 + l15][kk * 32 + lg * 8];

    int cb[8];
    #pragma unroll
    for (int jt = 0; jt < 8; jt++) {
        int col = jt * 16 + l15; if (col > 124) col = 124;
        const int q0 = col / 25, rem = col - q0 * 25, q1 = rem / 5, q2 = rem - q1 * 5;
        cb[jt] = 364 - (q0 * 81 + q1 * 9 + q2);
    }
    const size_t mbase = (size_t)(b & 255) * 15625;
    const float scale = 0.17677669529663689f;
    const v4f z4 = {0.f,0.f,0.f,0.f};

    for (int ch = 0; ch < 4; ch++) {
        v8bf qf[2];
        #pragma unroll
        for (int mt = 0; mt < 2; mt++) {
            int r = ch * 32 + mt * 16 + l15; if (r > 124) r = 124;
            qf[mt] = *(const v8bf*)&QL[r][lg * 8];
        }
        v4f acc[2][8];
        #pragma unroll
        for (int mt = 0; mt < 2; mt++)
            #pragma unroll
            for (int jt = 0; jt < 8; jt++) acc[mt][jt] = z4;
        #pragma unroll
        for (int jt = 0; jt < 8; jt++)
            #pragma unroll
            for (int mt = 0; mt < 2; mt++)
                acc[mt][jt] = MFMA(qf[mt], kf[jt], acc[mt][jt]);

        float rinv[2][4];
        #pragma unroll
        for (int mt = 0; mt < 2; mt++) {
            #pragma unroll
            for (int ri = 0; ri < 4; ri++) {
                const int row = ch * 32 + mt * 16 + lg * 4 + ri;
                const bool rv = row < 125;
                int prow = 0; size_t moff = 0;
                if (rv) {
                    const int p0 = row / 25, rem = row - p0 * 25, p1 = rem / 5, p2 = rem - p1 * 5;
                    prow = p0 * 81 + p1 * 9 + p2;
                    moff = mbase + (size_t)row * 125;
                }
                #pragma unroll
                for (int jt = 0; jt < 8; jt++) {
                    const int col = jt * 16 + l15;
                    float vv = -1e30f;
                    if (rv && col < 125)
                        vv = acc[mt][jt][ri] * scale
                           + load1(rpb, (size_t)(prow + cb[jt]) * 4 + h, f32)
                           + load1(msk, moff + col, f32);
                    acc[mt][jt][ri] = vv;
                }
                float mx = acc[mt][0][ri];
                #pragma unroll
                for (int jt = 1; jt < 8; jt++) mx = fmaxf(mx, acc[mt][jt][ri]);
                mx = fmaxf(mx, __shfl_xor(mx, 1));
                mx = fmaxf(mx, __shfl_xor(mx, 2));
                mx = fmaxf(mx, __shfl_xor(mx, 4));
                mx = fmaxf(mx, __shfl_xor(mx, 8));
                float sum = 0.f;
                #pragma unroll
                for (int jt = 0; jt < 8; jt++) {
                    const float pv = __expf(acc[mt][jt][ri] - mx);
                    acc[mt][jt][ri] = pv; sum += pv;
                }
                sum += __shfl_xor(sum, 1);
                sum += __shfl_xor(sum, 2);
                sum += __shfl_xor(sum, 4);
                sum += __shfl_xor(sum, 8);
                rinv[mt][ri] = 1.0f / sum;
            }
        }

        __syncthreads();
        #pragma unroll
        for (int mt = 0; mt < 2; mt++)
            #pragma unroll
            for (int jt = 0; jt < 8; jt++)
                #pragma unroll
                for (int ri = 0; ri < 4; ri++)
                    P[mt * 16 + lg * 4 + ri][jt * 16 + l15] = f2bf(acc[mt][jt][ri]);
        __syncthreads();

        v4f o[2][2];
        #pragma unroll
        for (int mt = 0; mt < 2; mt++)
            #pragma unroll
            for (int n2 = 0; n2 < 2; n2++) o[mt][n2] = z4;
        #pragma unroll
        for (int mt = 0; mt < 2; mt++) {
            v8bf pa[4];
            #pragma unroll
            for (int kk = 0; kk < 4; kk++)
                pa[kk] = *(const v8bf*)&P[mt * 16 + l15][kk * 32 + lg * 8];
            #pragma unroll
            for (int n2 = 0; n2 < 2; n2++)
                #pragma unroll
                for (int kk = 0; kk < 4; kk++)
                    o[mt][n2] = MFMA(pa[kk], vf[n2][kk], o[mt][n2]);
        }

        #pragma unroll
        for (int mt = 0; mt < 2; mt++)
            #pragma unroll
            for (int n2 = 0; n2 < 2; n2++)
                #pragma unroll
                for (int ri = 0; ri < 4; ri++) {
                    const int row = ch * 32 + mt * 16 + lg * 4 + ri;
                    if (row < 125)
                        out[((size_t)s * 256000 + (size_t)b * 125 + row) * 128
                            + h * 32 + n2 * 16 + l15] = o[mt][n2][ri] * rinv[mt][ri];
                }
    }
}

// ---- output projection, in place on fp32 d_out (fallback path only) ----
__global__ __launch_bounds__(256) void proj_kernel(
    const void* __restrict__ wpx, const void* __restrict__ bpx,
    const void* __restrict__ wpy, const void* __restrict__ bpy,
    const int* __restrict__ flag, float* io)
{
    const bool f32 = (*flag != 0);
    const int s  = blockIdx.y;
    const int bm = blockIdx.x;
    const void* W    = s ? wpy : wpx;
    const void* bias = s ? bpy : bpx;
    float* A = io + (size_t)s * 32768000;
    const int tid = threadIdx.x, lane = tid & 63, wv = tid >> 6;
    const int l15 = lane & 15, lg = lane >> 4;

    __shared__ u16 Wl[128][136];
    for (int i = tid * 8; i < 16384; i += 2048)
        *(v8bf*)&Wl[i >> 7][i & 127] = load8(W, i, f32);
    __syncthreads();

    const int mbase = bm * 64 + wv * 16;
    v4f acc[8];
    const v4f z4 = {0.f,0.f,0.f,0.f};
    #pragma unroll
    for (int nt = 0; nt < 8; nt++) acc[nt] = z4;

    const float* Ar = A + (size_t)(mbase + l15) * 128;
    v8bf afr[4];
    #pragma unroll
    for (int kk = 0; kk < 4; kk++) {
        union { u16 sI[8]; v8bf v; } U;
        float4 fa = *(const float4*)(Ar + kk * 32 + lg * 8);
        float4 fb = *(const float4*)(Ar + kk * 32 + lg * 8 + 4);
        U.sI[0] = f2bf(fa.x); U.sI[1] = f2bf(fa.y); U.sI[2] = f2bf(fa.z); U.sI[3] = f2bf(fa.w);
        U.sI[4] = f2bf(fb.x); U.sI[5] = f2bf(fb.y); U.sI[6] = f2bf(fb.z); U.sI[7] = f2bf(fb.w);
        afr[kk] = U.v;
    }
    #pragma unroll
    for (int kk = 0; kk < 4; kk++)
        #pragma unroll
        for (int nt = 0; nt < 8; nt++)
            acc[nt] = MFMA(afr[kk], *(const v8bf*)&Wl[nt * 16 + l15][kk * 32 + lg * 8], acc[nt]);

    #pragma unroll
    for (int nt = 0; nt < 8; nt++) {
        const int c = nt * 16 + l15;
        const float bv = load1(bias, c, f32);
        #pragma unroll
        for (int ri = 0; ri < 4; ri++)
            A[(size_t)(mbase + lg * 4 + ri) * 128 + c] = acc[nt][ri] + bv;
    }
}

extern "C" void kernel_launch(void* const* d_in, const int* in_sizes, int n_in,
                              void* d_out, int out_size, void* d_ws, size_t ws_size,
                              hipStream_t stream) {
    const float* x     = (const float*)d_in[0];
    const float* y     = (const float*)d_in[1];
    const float* maskx = (const float*)d_in[2];
    const float* masky = (const float*)d_in[3];
    const float* wqx   = (const float*)d_in[4];
    const float* bqx   = (const float*)d_in[5];
    const float* wqy   = (const float*)d_in[6];
    const float* bqy   = (const float*)d_in[7];
    const float* wpx   = (const float*)d_in[8];
    const float* bpx   = (const float*)d_in[9];
    const float* wpy   = (const float*)d_in[10];
    const float* bpy   = (const float*)d_in[11];
    const float* rpb   = (const float*)d_in[12];

    const size_t OFF_R0   = 0;
    const size_t OFF_Q    = 256000;
    const size_t OFF_K    = OFF_Q + 131072000;
    const size_t OFF_VT   = OFF_K + 131072000;
    const size_t OFF_WP   = OFF_VT + 134217728;
    const size_t OFF_BP   = OFF_WP + 65536;
    const size_t OFF_FLAG = OFF_BP + 512;
    const size_t NEED_MID = OFF_FLAG + 4;
    const size_t OFF_MT   = (NEED_MID + 15) & ~(size_t)15;
    const size_t NEED_BIG = OFF_MT + 32768000;                // 429,451,792
    const size_t OFF_RP   = NEED_BIG;
    const size_t NEED_BIG2 = OFF_RP + 256000;                 // 429,707,792
    const size_t OFF_CMB  = (NEED_BIG2 + 15) & ~(size_t)15;
    const size_t NEED_CMB = OFF_CMB + 131072000;              // ~560.8 MB (proven r18/r21)

    if (ws_size >= NEED_MID) {
        u16*   wb   = (u16*)((char*)d_ws + OFF_R0);
        u16*   bb   = wb + 98304;
        float* rpbR = (float*)((char*)d_ws + OFF_R0);   // region0 phase 2 (tiers B/C)
        u16*   q    = (u16*)((char*)d_ws + OFF_Q);
        u16*   k    = (u16*)((char*)d_ws + OFF_K);
        u16*   vT   = (u16*)((char*)d_ws + OFF_VT);
        u16*   wpb  = (u16*)((char*)d_ws + OFF_WP);
        u16*   bpb  = (u16*)((char*)d_ws + OFF_BP);

        wconv_kernel<<<dim3(256, 2), 256, 0, stream>>>(wqx, bqx, wqy, bqy,
                                                       wpx, bpx, wpy, bpy,
                                                       wb, bb, wpb, bpb);
        if (ws_size >= NEED_CMB) {
            // tier D (proven 554 us): sequential roles, gather cmb build
            float* cmbT = (float*)((char*)d_ws + OFF_CMB);
            qkvc_kernel<<<dim3(2048, 2), 256, 0, stream>>>(x, y, wb, bb,
                                                           maskx, masky, rpb,
                                                           q, k, vT, cmbT);
            attn_cmb<<<4096, 256, 0, stream>>>(q, k, vT, cmbT,
                                               wpb, bpb, (float*)d_out);
        } else if (ws_size >= NEED_BIG2) {
            // tier A: r17 proven path
            float* mskP = (float*)((char*)d_ws + OFF_MT);
            float* rpbP = (float*)((char*)d_ws + OFF_RP);
            qkvt_kernel<<<dim3(1282, 2), 256, 0, stream>>>(x, y, wb, bb,
                                                           maskx, masky, rpb,
                                                           q, k, vT, mskP, rpbP);
            attn_swp<<<4096, 256, 0, stream>>>(q, k, vT, mskP, rpbP,
                                               wpb, bpb, (float*)d_out);
        } else if (ws_size >= NEED_BIG) {
            // tier B: split launches
            float* mskP = (float*)((char*)d_ws + OFF_MT);
            qkv_kernel<<<dim3(1024, 2), 256, 0, stream>>>(x, y, wb, bb, q, k, vT);
            rpbp_kernel<<<4, 256, 0, stream>>>(rpb, rpbR);       // overwrites wb/bb
            mskp_kernel<<<dim3(256, 2), 256, 0, stream>>>(maskx, masky, mskP);
            attn_swp<<<4096, 256, 0, stream>>>(q, k, vT, mskP, rpbR,
                                               wpb, bpb, (float*)d_out);
        } else {
            // tier C: mid (mask staged in LDS)
            qkv_kernel<<<dim3(1024, 2), 256, 0, stream>>>(x, y, wb, bb, q, k, vT);
            rpbt_kernel<<<4, 256, 0, stream>>>(rpb, rpbR);       // col-major
            attn_mld_kernel<<<4096, 256, 0, stream>>>(q, k, vT, maskx, masky, rpbR,
                                                      wpb, bpb, (float*)d_out);
        }
    } else {
        int* flag = (int*)d_ws;
        probe_kernel<<<1, 64, 0, stream>>>((const unsigned*)x, flag);
        fused_attn<<<dim3(4096, 4), 64, 0, stream>>>(x, y, maskx, masky,
                                                     wqx, bqx, wqy, bqy,
                                                     rpb, flag, (float*)d_out);
        proj_kernel<<<dim3(4000, 2), 256, 0, stream>>>(wpx, bpx, wpy, bpy,
                                                       flag, (float*)d_out);
    }
}